// Round 1
// baseline (2447.418 us; speedup 1.0000x reference)
//
#include <hip/hip_runtime.h>
#include <math.h>

// ============================================================================
// VisionAttention: qkv GEMM -> rope -> segment-masked flash attention -> proj
// Round 1: all-fp32 correctness baseline (no MFMA yet; CDNA4 has no fp32 MFMA).
// Segment structure exploited: flash loop only covers [seg_start, seg_end).
// ============================================================================

#define N_TOK  4096
#define DIMM   1280
#define NHEAD  16
#define HD     80
#define QKVN   3840

#define QB 32
#define KB 32

// ---------------------------------------------------------------------------
// Generic fp32 GEMM: C = A(MxK) @ B(KxN) + bias.  64x64 tile, 256 thr, 4x4/thr.
// EPI==0: plain row-major write to out[M][N].
// EPI==1: qkv scatter: col m -> (part,h,d); out[((part*16+h)*N_TOK + n)*HD + d]
// ---------------------------------------------------------------------------
template<int EPI>
__global__ __launch_bounds__(256)
void gemm_kernel(const float* __restrict__ A, const float* __restrict__ B,
                 const float* __restrict__ bias, float* __restrict__ out,
                 int M, int Ncols, int K)
{
    __shared__ float As[16][68];   // [k][m] (transposed), pad 68 = conflict-free
    __shared__ float Bs[16][68];   // [k][n]

    const int tid  = threadIdx.x;
    const int row0 = blockIdx.x * 64;
    const int col0 = blockIdx.y * 64;
    const int tx   = tid & 15;
    const int ty   = tid >> 4;

    // global load indices
    const int ar = tid >> 2;         // 0..63 : A row within tile
    const int ak = (tid & 3) << 2;   // 0,4,8,12 : A k offset
    const int br = tid >> 4;         // 0..15 : B k row
    const int bc = (tid & 15) << 2;  // 0..60 : B col offset

    float acc[4][4] = {};

    for (int k0 = 0; k0 < K; k0 += 16) {
        const float4 av = *reinterpret_cast<const float4*>(
            &A[(size_t)(row0 + ar) * K + k0 + ak]);
        const float4 bv = *reinterpret_cast<const float4*>(
            &B[(size_t)(k0 + br) * Ncols + col0 + bc]);
        As[ak + 0][ar] = av.x;
        As[ak + 1][ar] = av.y;
        As[ak + 2][ar] = av.z;
        As[ak + 3][ar] = av.w;
        *reinterpret_cast<float4*>(&Bs[br][bc]) = bv;
        __syncthreads();

        #pragma unroll
        for (int k = 0; k < 16; ++k) {
            float4 a4 = *reinterpret_cast<const float4*>(&As[k][ty << 2]);
            float4 b4 = *reinterpret_cast<const float4*>(&Bs[k][tx << 2]);
            float aa[4] = {a4.x, a4.y, a4.z, a4.w};
            float bb[4] = {b4.x, b4.y, b4.z, b4.w};
            #pragma unroll
            for (int i = 0; i < 4; ++i)
                #pragma unroll
                for (int j = 0; j < 4; ++j)
                    acc[i][j] += aa[i] * bb[j];
        }
        __syncthreads();
    }

    #pragma unroll
    for (int i = 0; i < 4; ++i) {
        const int n = row0 + (ty << 2) + i;
        #pragma unroll
        for (int j = 0; j < 4; ++j) {
            const int m = col0 + (tx << 2) + j;
            float c = acc[i][j] + bias[m];
            if (EPI == 0) {
                out[(size_t)n * Ncols + m] = c;
            } else {
                const int part = m / DIMM;        // 0=q 1=k 2=v
                const int rem  = m - part * DIMM;
                const int h    = rem / HD;
                const int d    = rem - h * HD;
                out[(((size_t)(part * NHEAD + h)) * N_TOK + n) * HD + d] = c;
            }
        }
    }
}

// ---------------------------------------------------------------------------
// Rotary: in-place on q,k (head-major [H][N][D]). One thread per (n,h,dpair).
// out[d]    = x[d]*cos(f[d]) - x[d+40]*sin(f[d])
// out[d+40] = x[d+40]*cos(f[d]) + x[d]*sin(f[d])
// ---------------------------------------------------------------------------
__global__ void rope_kernel(const float* __restrict__ freqs,
                            float* __restrict__ q, float* __restrict__ k)
{
    const int idx = blockIdx.x * blockDim.x + threadIdx.x;
    if (idx >= N_TOK * NHEAD * 40) return;
    const int dp = idx % 40;
    const int t  = idx / 40;
    const int h  = t & 15;
    const int n  = t >> 4;

    const float f = freqs[n * 40 + dp];
    const float c = cosf(f);
    const float s = sinf(f);

    const size_t base = ((size_t)h * N_TOK + n) * HD;
    const float q1 = q[base + dp], q2 = q[base + dp + 40];
    q[base + dp]      = q1 * c - q2 * s;
    q[base + dp + 40] = q2 * c + q1 * s;
    const float k1 = k[base + dp], k2 = k[base + dp + 40];
    k[base + dp]      = k1 * c - k2 * s;
    k[base + dp + 40] = k2 * c + k1 * s;
}

// ---------------------------------------------------------------------------
// Flash attention per (head, 32-row q-tile) over same-segment keys only.
// 256 threads. Scores: 2x2 per thread. Online softmax rows by threads 0..31.
// O accumulator: thread owns (row = tid/8, d = (tid%8)*10 .. +9) : 10 regs.
// ---------------------------------------------------------------------------
__global__ __launch_bounds__(256)
void attn_kernel(const float* __restrict__ qb, const float* __restrict__ kb,
                 const float* __restrict__ vb, const int* __restrict__ cu,
                 float* __restrict__ attn_out)
{
    __shared__ float Qs[QB][84];
    __shared__ float Ks[KB][84];
    __shared__ float Vs[KB][84];
    __shared__ float Sm[QB][KB + 1];
    __shared__ float rm[QB], rl[QB], rsf[QB];
    __shared__ int   rseg[QB], kseg[KB];

    const int tid = threadIdx.x;
    const int h   = blockIdx.y;
    const int q0  = blockIdx.x * QB;

    const int c1 = cu[1], c2 = cu[2], c3 = cu[3];
    #define SEGOF(n) ((int)((n) >= c1) + (int)((n) >= c2) + (int)((n) >= c3))

    const int seg_first = SEGOF(q0);
    const int seg_last  = SEGOF(q0 + QB - 1);
    const int cuv[5] = {0, c1, c2, c3, N_TOK};
    const int kmin = cuv[seg_first];
    const int kmax = cuv[seg_last + 1];

    const int li = tid >> 3;          // 0..31
    const int ld = (tid & 7) * 10;    // 0,10,...,70

    {
        const int n = q0 + li;
        const size_t base = ((size_t)h * N_TOK + n) * HD;
        #pragma unroll
        for (int l = 0; l < 10; ++l) Qs[li][ld + l] = qb[base + ld + l];
        if (tid < QB) {
            rseg[tid] = SEGOF(q0 + tid);
            rm[tid] = -1e30f;
            rl[tid] = 0.f;
        }
    }

    float o[10];
    #pragma unroll
    for (int l = 0; l < 10; ++l) o[l] = 0.f;

    const float scale = 0.11180339887498949f;  // 1/sqrt(80)

    for (int kt = kmin; kt < kmax; kt += KB) {
        // ---- stage K/V tile
        {
            const int n = kt + li;
            if (n < N_TOK) {
                const size_t base = ((size_t)h * N_TOK + n) * HD;
                #pragma unroll
                for (int l = 0; l < 10; ++l) {
                    Ks[li][ld + l] = kb[base + ld + l];
                    Vs[li][ld + l] = vb[base + ld + l];
                }
            } else {
                #pragma unroll
                for (int l = 0; l < 10; ++l) { Ks[li][ld + l] = 0.f; Vs[li][ld + l] = 0.f; }
            }
            if (tid < KB) {
                const int n2 = kt + tid;
                kseg[tid] = (n2 < N_TOK) ? SEGOF(n2) : -1;
            }
        }
        __syncthreads();

        // ---- scores 2x2 per thread
        {
            const int i0 = (tid >> 4) << 1;
            const int j0 = (tid & 15) << 1;
            float s00 = 0.f, s01 = 0.f, s10 = 0.f, s11 = 0.f;
            #pragma unroll
            for (int d = 0; d < HD; d += 2) {
                const float2 qa = *reinterpret_cast<const float2*>(&Qs[i0][d]);
                const float2 qc = *reinterpret_cast<const float2*>(&Qs[i0 + 1][d]);
                const float2 ka = *reinterpret_cast<const float2*>(&Ks[j0][d]);
                const float2 kc = *reinterpret_cast<const float2*>(&Ks[j0 + 1][d]);
                s00 += qa.x * ka.x + qa.y * ka.y;
                s01 += qa.x * kc.x + qa.y * kc.y;
                s10 += qc.x * ka.x + qc.y * ka.y;
                s11 += qc.x * kc.x + qc.y * kc.y;
            }
            Sm[i0][j0]         = s00 * scale;
            Sm[i0][j0 + 1]     = s01 * scale;
            Sm[i0 + 1][j0]     = s10 * scale;
            Sm[i0 + 1][j0 + 1] = s11 * scale;
        }
        __syncthreads();

        // ---- online softmax per row (threads 0..31)
        if (tid < QB) {
            const int i = tid, myseg = rseg[i];
            float mt = -1e30f;
            #pragma unroll 8
            for (int j = 0; j < KB; ++j)
                if (kseg[j] == myseg) mt = fmaxf(mt, Sm[i][j]);
            const float mo = rm[i];
            const float mn = fmaxf(mo, mt);
            const float sf = __expf(mo - mn);   // both -1e30 -> exp(0)=1, harmless
            float sum = 0.f;
            #pragma unroll 8
            for (int j = 0; j < KB; ++j) {
                const float p = (kseg[j] == myseg) ? __expf(Sm[i][j] - mn) : 0.f;
                Sm[i][j] = p;                    // reuse Sm as P
                sum += p;
            }
            rl[i]  = rl[i] * sf + sum;
            rm[i]  = mn;
            rsf[i] = sf;
        }
        __syncthreads();

        // ---- O = O*sf + P @ V
        {
            const float sf = rsf[li];
            #pragma unroll
            for (int l = 0; l < 10; ++l) o[l] *= sf;
            #pragma unroll 4
            for (int j = 0; j < KB; ++j) {
                const float p = Sm[li][j];
                #pragma unroll
                for (int l = 0; l < 10; ++l) o[l] += p * Vs[j][ld + l];
            }
        }
        __syncthreads();
    }

    const float inv = 1.f / rl[li];
    const int n = q0 + li;
    const size_t ob = (size_t)n * DIMM + (size_t)h * HD + ld;
    #pragma unroll
    for (int l = 0; l < 10; ++l) attn_out[ob + l] = o[l] * inv;
    #undef SEGOF
}

// ---------------------------------------------------------------------------
extern "C" void kernel_launch(void* const* d_in, const int* in_sizes, int n_in,
                              void* d_out, int out_size, void* d_ws, size_t ws_size,
                              hipStream_t stream)
{
    const float* hidden = (const float*)d_in[0];
    const int*   cu     = (const int*)  d_in[1];
    const float* rope   = (const float*)d_in[2];
    const float* w_qkv  = (const float*)d_in[3];
    const float* b_qkv  = (const float*)d_in[4];
    const float* w_proj = (const float*)d_in[5];
    const float* b_proj = (const float*)d_in[6];
    float*       out    = (float*)d_out;

    const size_t perbuf = (size_t)NHEAD * N_TOK * HD;   // 5,242,880 floats
    float* qbuf = (float*)d_ws;
    float* kbuf = qbuf + perbuf;
    float* vbuf = kbuf + perbuf;
    float* abuf = vbuf + perbuf;                        // [N_TOK][DIMM]

    // 1) QKV GEMM + bias, scatter to head-major q/k/v
    {
        dim3 grid(N_TOK / 64, QKVN / 64);
        gemm_kernel<1><<<grid, 256, 0, stream>>>(hidden, w_qkv, b_qkv, qbuf,
                                                 N_TOK, QKVN, DIMM);
    }
    // 2) rotary in place on q,k
    {
        const int total = N_TOK * NHEAD * 40;
        rope_kernel<<<(total + 255) / 256, 256, 0, stream>>>(rope, qbuf, kbuf);
    }
    // 3) segment-masked flash attention
    {
        dim3 grid(N_TOK / QB, NHEAD);
        attn_kernel<<<grid, 256, 0, stream>>>(qbuf, kbuf, vbuf, cu, abuf);
    }
    // 4) proj GEMM + bias -> out
    {
        dim3 grid(N_TOK / 64, DIMM / 64);
        gemm_kernel<0><<<grid, 256, 0, stream>>>(abuf, w_proj, b_proj, out,
                                                 N_TOK, DIMM, DIMM);
    }
}

// Round 2
// 1058.273 us; speedup vs baseline: 2.3127x; 2.3127x over previous
//
#include <hip/hip_runtime.h>
#include <math.h>

// ============================================================================
// VisionAttention, round 2: bf16-MFMA everywhere, fp32 accuracy via hi/lo split.
//   pack_A:   hidden fp32 -> A' = [Ah | Al | Ah]            (M x 3K bf16)
//   pack_Bt:  W fp32      -> Bt' = [Bh | Bh | Bl] transposed (N x 3K bf16)
//   gemm_mfma: C = A'(Mx3K) @ Bt'(Nx3K)^T  == Ah@Bh + Al@Bh + Ah@Bl ~= fp32
//   rope:     fp32 in place
//   attn_mfma: flash attention, QK^T with Q,K hi/lo (3 mfma), PV with V hi/lo,
//              wave-parallel online softmax; writes packed A' for proj GEMM.
// ============================================================================

#define N_TOK 4096
#define DIMM  1280
#define NHEAD 16
#define HD    80
#define QKVN  3840
#define KP    3840   // packed K' = 3*DIMM

typedef short bf16x8 __attribute__((ext_vector_type(8)));
typedef float f32x4  __attribute__((ext_vector_type(4)));

__device__ __forceinline__ unsigned short f2bf(float x) {
    unsigned int u = __float_as_uint(x);
    u += 0x7fff + ((u >> 16) & 1);           // RNE
    return (unsigned short)(u >> 16);
}
__device__ __forceinline__ float bf2f(unsigned short h) {
    return __uint_as_float(((unsigned int)h) << 16);
}
__device__ __forceinline__ void gload_lds16(const void* g, void* l) {
    __builtin_amdgcn_global_load_lds(
        (const __attribute__((address_space(1))) unsigned int*)g,
        (__attribute__((address_space(3))) unsigned int*)l, 16, 0, 0);
}

#define MFMA16(a, b, c) __builtin_amdgcn_mfma_f32_16x16x32_bf16((a), (b), (c), 0, 0, 0)

// ---------------------------------------------------------------------------
// pack hidden: X[M][1280] fp32 -> Ap[M][3840] bf16 = [hi | lo | hi]
// ---------------------------------------------------------------------------
__global__ void pack_A_kernel(const float* __restrict__ X, unsigned short* __restrict__ Ap)
{
    const int idx = blockIdx.x * blockDim.x + threadIdx.x;
    if (idx >= N_TOK * DIMM / 4) return;
    const int e = idx * 4;
    const int m = e / DIMM, k = e - (e / DIMM) * DIMM;
    const float4 v = *reinterpret_cast<const float4*>(&X[(size_t)m * DIMM + k]);
    ushort4 hi, lo;
    hi.x = f2bf(v.x); lo.x = f2bf(v.x - bf2f(hi.x));
    hi.y = f2bf(v.y); lo.y = f2bf(v.y - bf2f(hi.y));
    hi.z = f2bf(v.z); lo.z = f2bf(v.z - bf2f(hi.z));
    hi.w = f2bf(v.w); lo.w = f2bf(v.w - bf2f(hi.w));
    const size_t base = (size_t)m * KP + k;
    *reinterpret_cast<ushort4*>(&Ap[base])            = hi;
    *reinterpret_cast<ushort4*>(&Ap[base + DIMM])     = lo;
    *reinterpret_cast<ushort4*>(&Ap[base + 2 * DIMM]) = hi;
}

// ---------------------------------------------------------------------------
// pack weight transposed: W[1280][Ncols] fp32 -> Bt[Ncols][3840] = [hi | hi | lo]
// ---------------------------------------------------------------------------
__global__ __launch_bounds__(256)
void pack_Bt_kernel(const float* __restrict__ W, unsigned short* __restrict__ Bt, int Ncols)
{
    __shared__ float Ts[32][33];
    const int k0 = blockIdx.x * 32, n0 = blockIdx.y * 32;
    const int t = threadIdx.x;
    const int r = t >> 3, c4 = (t & 7) * 4;
    const float4 v = *reinterpret_cast<const float4*>(&W[(size_t)(k0 + r) * Ncols + n0 + c4]);
    Ts[r][c4] = v.x; Ts[r][c4 + 1] = v.y; Ts[r][c4 + 2] = v.z; Ts[r][c4 + 3] = v.w;
    __syncthreads();
    float w0 = Ts[c4][r], w1 = Ts[c4 + 1][r], w2 = Ts[c4 + 2][r], w3 = Ts[c4 + 3][r];
    ushort4 hi, lo;
    hi.x = f2bf(w0); lo.x = f2bf(w0 - bf2f(hi.x));
    hi.y = f2bf(w1); lo.y = f2bf(w1 - bf2f(hi.y));
    hi.z = f2bf(w2); lo.z = f2bf(w2 - bf2f(hi.z));
    hi.w = f2bf(w3); lo.w = f2bf(w3 - bf2f(hi.w));
    const size_t base = (size_t)(n0 + r) * KP + k0 + c4;
    *reinterpret_cast<ushort4*>(&Bt[base])            = hi;
    *reinterpret_cast<ushort4*>(&Bt[base + DIMM])     = hi;
    *reinterpret_cast<ushort4*>(&Bt[base + 2 * DIMM]) = lo;
}

// ---------------------------------------------------------------------------
// bf16 MFMA GEMM: C[M][Ncols] = A(MxKP) @ Bt(NcolsxKP)^T + bias
// 128x128 tile, 4 waves (2x2), 4x4 16x16x32 frags/wave, BK=32, m97 structure.
// EPI==0: plain write.  EPI==1: qkv scatter to [part][h][n][d].
// ---------------------------------------------------------------------------
template<int EPI>
__global__ __launch_bounds__(256)
void gemm_mfma(const unsigned short* __restrict__ A, const unsigned short* __restrict__ Bt,
               const float* __restrict__ bias, float* __restrict__ out, int Ncols)
{
    __shared__ unsigned short As[128 * 32];
    __shared__ unsigned short Bs[128 * 32];

    const int tid  = threadIdx.x;
    const int w    = tid >> 6, lane = tid & 63;
    const int m0   = blockIdx.x * 128, n0 = blockIdx.y * 128;
    const int wm   = w >> 1, wn = w & 1;
    const int lm   = lane & 15, kb = lane >> 4;

    const char* Ag = (const char*)(A  + (size_t)(m0 + w * 32 + (lane >> 2)) * KP) + (lane & 3) * 16;
    const char* Bg = (const char*)(Bt + (size_t)(n0 + w * 32 + (lane >> 2)) * KP) + (lane & 3) * 16;
    char* AsB = (char*)As + w * 2048;
    char* BsB = (char*)Bs + w * 2048;
    const size_t rowskip = (size_t)16 * KP * 2;   // +16 rows in bytes

    f32x4 acc[4][4] = {};

    for (int k0 = 0; k0 < KP; k0 += 32) {
        const size_t kb2 = (size_t)k0 * 2;
        gload_lds16(Ag + kb2,           AsB);
        gload_lds16(Ag + kb2 + rowskip, AsB + 1024);
        gload_lds16(Bg + kb2,           BsB);
        gload_lds16(Bg + kb2 + rowskip, BsB + 1024);
        __syncthreads();

        bf16x8 a[4], b[4];
        #pragma unroll
        for (int mf = 0; mf < 4; ++mf)
            a[mf] = *reinterpret_cast<const bf16x8*>(&As[(wm * 64 + mf * 16 + lm) * 32 + kb * 8]);
        #pragma unroll
        for (int nf = 0; nf < 4; ++nf)
            b[nf] = *reinterpret_cast<const bf16x8*>(&Bs[(wn * 64 + nf * 16 + lm) * 32 + kb * 8]);
        #pragma unroll
        for (int mf = 0; mf < 4; ++mf)
            #pragma unroll
            for (int nf = 0; nf < 4; ++nf)
                acc[mf][nf] = MFMA16(a[mf], b[nf], acc[mf][nf]);
        __syncthreads();
    }

    #pragma unroll
    for (int nf = 0; nf < 4; ++nf) {
        const int col = n0 + wn * 64 + nf * 16 + lm;
        const float bb = bias[col];
        #pragma unroll
        for (int mf = 0; mf < 4; ++mf) {
            #pragma unroll
            for (int r = 0; r < 4; ++r) {
                const int row = m0 + wm * 64 + mf * 16 + kb * 4 + r;
                const float c = acc[mf][nf][r] + bb;
                if (EPI == 0) {
                    out[(size_t)row * Ncols + col] = c;
                } else {
                    const int part = col / DIMM;
                    const int rem  = col - part * DIMM;
                    const int hh   = rem / HD;
                    const int d    = rem - hh * HD;
                    out[(((size_t)(part * NHEAD + hh)) * N_TOK + row) * HD + d] = c;
                }
            }
        }
    }
}

// ---------------------------------------------------------------------------
// Rotary, fp32 in place (unchanged from round 1 — verified).
// ---------------------------------------------------------------------------
__global__ void rope_kernel(const float* __restrict__ freqs,
                            float* __restrict__ q, float* __restrict__ k)
{
    const int idx = blockIdx.x * blockDim.x + threadIdx.x;
    if (idx >= N_TOK * NHEAD * 40) return;
    const int dp = idx % 40;
    const int t  = idx / 40;
    const int h  = t & 15;
    const int n  = t >> 4;

    const float f = freqs[n * 40 + dp];
    const float c = cosf(f);
    const float s = sinf(f);

    const size_t base = ((size_t)h * N_TOK + n) * HD;
    const float q1 = q[base + dp], q2 = q[base + dp + 40];
    q[base + dp]      = q1 * c - q2 * s;
    q[base + dp + 40] = q2 * c + q1 * s;
    const float k1 = k[base + dp], k2 = k[base + dp + 40];
    k[base + dp]      = k1 * c - k2 * s;
    k[base + dp + 40] = k2 * c + k1 * s;
}

// ---------------------------------------------------------------------------
// MFMA flash attention. Block = 4 waves; wave w owns 16 q-rows. 32-key tiles.
// QK^T: 3-term hi/lo (d padded to 96). PV: P bf16, V hi/lo.
// Epilogue writes packed A' = [hi | lo | hi] rows for the proj GEMM.
// ---------------------------------------------------------------------------
__global__ __launch_bounds__(256)
void attn_mfma(const float* __restrict__ qb, const float* __restrict__ kbp,
               const float* __restrict__ vbp, const int* __restrict__ cu,
               unsigned short* __restrict__ Ap)
{
    __shared__ unsigned short Ksh[32 * 104], Ksl[32 * 104];   // [key][dpad104]
    __shared__ unsigned short Vth[80 * 40],  Vtl[80 * 40];    // [d][keypad40]
    __shared__ unsigned short Pw[4][16 * 40];                 // per-wave P
    __shared__ int ksegs[32];

    const int tid  = threadIdx.x;
    const int w    = tid >> 6, lane = tid & 63;
    const int lm   = lane & 15, g = lane >> 4;
    const int h    = blockIdx.y;
    const int q0   = blockIdx.x * 64;
    const int c1 = cu[1], c2 = cu[2], c3 = cu[3];

    #define SEGOF(n) ((int)((n) >= c1) + (int)((n) >= c2) + (int)((n) >= c3))
    const int seg_first = SEGOF(q0);
    const int seg_last  = SEGOF(q0 + 63);
    const int cuv[5] = {0, c1, c2, c3, N_TOK};
    const int kmin = cuv[seg_first], kmax = cuv[seg_last + 1];

    const size_t hb = (size_t)h * N_TOK;

    // --- Q fragments (scale folded in), hi/lo
    bf16x8 qh[3], ql[3];
    {
        const int qrow = q0 + w * 16 + lm;
        #pragma unroll
        for (int ks = 0; ks < 3; ++ks) {
            #pragma unroll
            for (int j = 0; j < 8; ++j) {
                const int d = ks * 32 + g * 8 + j;
                float x = (d < HD) ? qb[(hb + qrow) * HD + d] * 0.11180339887498949f : 0.f;
                const unsigned short hi = f2bf(x);
                qh[ks][j] = (short)hi;
                ql[ks][j] = (short)f2bf(x - bf2f(hi));
            }
        }
    }
    int qsg[4];
    #pragma unroll
    for (int r = 0; r < 4; ++r) qsg[r] = SEGOF(q0 + w * 16 + g * 4 + r);

    float mrun[4] = {-1e30f, -1e30f, -1e30f, -1e30f};
    float lrun[4] = {0.f, 0.f, 0.f, 0.f};
    f32x4 accO[5] = {};

    for (int kt = kmin; kt < kmax; kt += 32) {
        __syncthreads();   // all waves done reading previous K/V tile
        // ---- stage K (hi/lo, padded) and V^T (hi/lo)
        #pragma unroll
        for (int i = 0; i < 10; ++i) {
            const int e = i * 256 + tid;           // 0..2559
            const int key = e / 80, d = e - (e / 80) * 80;
            const int n = kt + key;
            float kx = 0.f, vx = 0.f;
            if (n < kmax) {
                kx = kbp[(hb + n) * HD + d];
                vx = vbp[(hb + n) * HD + d];
            }
            const unsigned short khh = f2bf(kx);
            Ksh[key * 104 + d] = khh;
            Ksl[key * 104 + d] = f2bf(kx - bf2f(khh));
            const unsigned short vhh = f2bf(vx);
            Vth[d * 40 + key] = vhh;
            Vtl[d * 40 + key] = f2bf(vx - bf2f(vhh));
        }
        #pragma unroll
        for (int i = 0; i < 2; ++i) {              // zero-pad d = 80..95
            const int e = i * 256 + tid;
            const int key = e >> 4, d = 80 + (e & 15);
            Ksh[key * 104 + d] = 0;
            Ksl[key * 104 + d] = 0;
        }
        if (tid < 32) {
            const int n = kt + tid;
            ksegs[tid] = (n < kmax) ? SEGOF(n) : -1;
        }
        __syncthreads();

        // ---- S = Q @ K^T  (two 16-key blocks)
        f32x4 s0 = {0.f, 0.f, 0.f, 0.f}, s1 = {0.f, 0.f, 0.f, 0.f};
        #pragma unroll
        for (int ks = 0; ks < 3; ++ks) {
            const bf16x8 k0h = *reinterpret_cast<const bf16x8*>(&Ksh[lm * 104 + ks * 32 + g * 8]);
            const bf16x8 k0l = *reinterpret_cast<const bf16x8*>(&Ksl[lm * 104 + ks * 32 + g * 8]);
            const bf16x8 k1h = *reinterpret_cast<const bf16x8*>(&Ksh[(16 + lm) * 104 + ks * 32 + g * 8]);
            const bf16x8 k1l = *reinterpret_cast<const bf16x8*>(&Ksl[(16 + lm) * 104 + ks * 32 + g * 8]);
            s0 = MFMA16(qh[ks], k0h, s0);
            s0 = MFMA16(ql[ks], k0h, s0);
            s0 = MFMA16(qh[ks], k0l, s0);
            s1 = MFMA16(qh[ks], k1h, s1);
            s1 = MFMA16(ql[ks], k1h, s1);
            s1 = MFMA16(qh[ks], k1l, s1);
        }

        // ---- online softmax (rows live in 16-lane groups; butterfly reduce)
        const int ks0 = ksegs[lm], ks1 = ksegs[16 + lm];
        float sfr[4], p0v[4], p1v[4];
        #pragma unroll
        for (int r = 0; r < 4; ++r) {
            const bool u0 = (ks0 == qsg[r]), u1 = (ks1 == qsg[r]);
            float v0 = u0 ? s0[r] : -1e30f;
            float v1 = u1 ? s1[r] : -1e30f;
            float tm = fmaxf(v0, v1);
            tm = fmaxf(tm, __shfl_xor(tm, 1));
            tm = fmaxf(tm, __shfl_xor(tm, 2));
            tm = fmaxf(tm, __shfl_xor(tm, 4));
            tm = fmaxf(tm, __shfl_xor(tm, 8));
            const float mo = mrun[r];
            const float mn = fmaxf(mo, tm);
            const float sc = __expf(mo - mn);
            const float e0 = u0 ? __expf(s0[r] - mn) : 0.f;
            const float e1 = u1 ? __expf(s1[r] - mn) : 0.f;
            float rs = e0 + e1;
            rs += __shfl_xor(rs, 1);
            rs += __shfl_xor(rs, 2);
            rs += __shfl_xor(rs, 4);
            rs += __shfl_xor(rs, 8);
            lrun[r] = lrun[r] * sc + rs;
            mrun[r] = mn;
            sfr[r] = sc; p0v[r] = e0; p1v[r] = e1;
        }
        #pragma unroll
        for (int r = 0; r < 4; ++r) {
            Pw[w][(g * 4 + r) * 40 + lm]      = f2bf(p0v[r]);
            Pw[w][(g * 4 + r) * 40 + 16 + lm] = f2bf(p1v[r]);
        }
        asm volatile("s_waitcnt lgkmcnt(0)" ::: "memory");   // cross-lane P visibility

        // ---- O = O*sf + P @ (Vh + Vl)
        const bf16x8 pa = *reinterpret_cast<const bf16x8*>(&Pw[w][lm * 40 + g * 8]);
        #pragma unroll
        for (int f = 0; f < 5; ++f) {
            const bf16x8 vh = *reinterpret_cast<const bf16x8*>(&Vth[(f * 16 + lm) * 40 + g * 8]);
            const bf16x8 vl = *reinterpret_cast<const bf16x8*>(&Vtl[(f * 16 + lm) * 40 + g * 8]);
            f32x4 t = accO[f];
            t[0] *= sfr[0]; t[1] *= sfr[1]; t[2] *= sfr[2]; t[3] *= sfr[3];
            t = MFMA16(pa, vh, t);
            t = MFMA16(pa, vl, t);
            accO[f] = t;
        }
    }

    // ---- epilogue: write packed A' rows [hi | lo | hi]
    #pragma unroll
    for (int r = 0; r < 4; ++r) {
        const float inv = 1.f / lrun[r];
        const int n = q0 + w * 16 + g * 4 + r;
        const size_t rb = (size_t)n * KP + h * HD;
        #pragma unroll
        for (int f = 0; f < 5; ++f) {
            const float v = accO[f][r] * inv;
            const unsigned short hi = f2bf(v);
            const unsigned short lo = f2bf(v - bf2f(hi));
            Ap[rb + f * 16 + lm]            = hi;
            Ap[rb + DIMM + f * 16 + lm]     = lo;
            Ap[rb + 2 * DIMM + f * 16 + lm] = hi;
        }
    }
    #undef SEGOF
}

// ---------------------------------------------------------------------------
extern "C" void kernel_launch(void* const* d_in, const int* in_sizes, int n_in,
                              void* d_out, int out_size, void* d_ws, size_t ws_size,
                              hipStream_t stream)
{
    const float* hidden = (const float*)d_in[0];
    const int*   cu     = (const int*)  d_in[1];
    const float* rope   = (const float*)d_in[2];
    const float* w_qkv  = (const float*)d_in[3];
    const float* b_qkv  = (const float*)d_in[4];
    const float* w_proj = (const float*)d_in[5];
    const float* b_proj = (const float*)d_in[6];
    float*       out    = (float*)d_out;

    const size_t perbuf = (size_t)NHEAD * N_TOK * HD;          // floats
    float* qbuf = (float*)d_ws;
    float* kbuf = qbuf + perbuf;
    float* vbuf = kbuf + perbuf;
    unsigned short* Apack = (unsigned short*)(vbuf + perbuf);  // [4096][3840], reused
    unsigned short* BtQ   = Apack + (size_t)N_TOK * KP;        // [3840][3840]
    unsigned short* BtP   = BtQ + (size_t)QKVN * KP;           // [1280][3840]

    pack_A_kernel<<<(N_TOK * DIMM / 4 + 255) / 256, 256, 0, stream>>>(hidden, Apack);
    pack_Bt_kernel<<<dim3(DIMM / 32, QKVN / 32), 256, 0, stream>>>(w_qkv, BtQ, QKVN);
    pack_Bt_kernel<<<dim3(DIMM / 32, DIMM / 32), 256, 0, stream>>>(w_proj, BtP, DIMM);

    gemm_mfma<1><<<dim3(N_TOK / 128, QKVN / 128), 256, 0, stream>>>(Apack, BtQ, b_qkv, qbuf, QKVN);

    rope_kernel<<<(N_TOK * NHEAD * 40 + 255) / 256, 256, 0, stream>>>(rope, qbuf, kbuf);

    attn_mfma<<<dim3(N_TOK / 64, NHEAD), 256, 0, stream>>>(qbuf, kbuf, vbuf, cu, Apack);

    gemm_mfma<0><<<dim3(N_TOK / 128, DIMM / 128), 256, 0, stream>>>(Apack, BtP, b_proj, out, DIMM);
}

// Round 3
// 624.059 us; speedup vs baseline: 3.9218x; 1.6958x over previous
//
#include <hip/hip_runtime.h>
#include <math.h>

// ============================================================================
// VisionAttention round 3.
//   Round-2 bottleneck: attn staged K/V as fp32 + per-tile hi/lo conversion
//   (re-converted ~34x per element) with 2 barriers/tile. Now: K,V pre-packed
//   ONCE in global as bf16 hi/lo in LDS-tile byte layout; attention staging is
//   pure global_load_lds (async DMA), double-buffered, 1 barrier/tile.
// ============================================================================

#define N_TOK 4096
#define DIMM  1280
#define NHEAD 16
#define HD    80
#define QKVN  3840
#define KP    3840   // packed K' = 3*DIMM for the hi/lo GEMM trick

typedef short bf16x8 __attribute__((ext_vector_type(8)));
typedef float f32x4  __attribute__((ext_vector_type(4)));

__device__ __forceinline__ unsigned short f2bf(float x) {
    unsigned int u = __float_as_uint(x);
    u += 0x7fff + ((u >> 16) & 1);           // RNE
    return (unsigned short)(u >> 16);
}
__device__ __forceinline__ float bf2f(unsigned short h) {
    return __uint_as_float(((unsigned int)h) << 16);
}
__device__ __forceinline__ void gload_lds16(const void* g, void* l) {
    __builtin_amdgcn_global_load_lds(
        (const __attribute__((address_space(1))) unsigned int*)g,
        (__attribute__((address_space(3))) unsigned int*)l, 16, 0, 0);
}

#define MFMA16(a, b, c) __builtin_amdgcn_mfma_f32_16x16x32_bf16((a), (b), (c), 0, 0, 0)

// ---------------------------------------------------------------------------
// pack hidden: X[M][1280] fp32 -> Ap[M][3840] bf16 = [hi | lo | hi]
// ---------------------------------------------------------------------------
__global__ void pack_A_kernel(const float* __restrict__ X, unsigned short* __restrict__ Ap)
{
    const int idx = blockIdx.x * blockDim.x + threadIdx.x;
    if (idx >= N_TOK * DIMM / 4) return;
    const int e = idx * 4;
    const int m = e / DIMM, k = e - (e / DIMM) * DIMM;
    const float4 v = *reinterpret_cast<const float4*>(&X[(size_t)m * DIMM + k]);
    ushort4 hi, lo;
    hi.x = f2bf(v.x); lo.x = f2bf(v.x - bf2f(hi.x));
    hi.y = f2bf(v.y); lo.y = f2bf(v.y - bf2f(hi.y));
    hi.z = f2bf(v.z); lo.z = f2bf(v.z - bf2f(hi.z));
    hi.w = f2bf(v.w); lo.w = f2bf(v.w - bf2f(hi.w));
    const size_t base = (size_t)m * KP + k;
    *reinterpret_cast<ushort4*>(&Ap[base])            = hi;
    *reinterpret_cast<ushort4*>(&Ap[base + DIMM])     = lo;
    *reinterpret_cast<ushort4*>(&Ap[base + 2 * DIMM]) = hi;
}

// ---------------------------------------------------------------------------
// pack weight transposed: W[1280][Ncols] fp32 -> Bt[Ncols][3840] = [hi | hi | lo]
// ---------------------------------------------------------------------------
__global__ __launch_bounds__(256)
void pack_Bt_kernel(const float* __restrict__ W, unsigned short* __restrict__ Bt, int Ncols)
{
    __shared__ float Ts[32][33];
    const int k0 = blockIdx.x * 32, n0 = blockIdx.y * 32;
    const int t = threadIdx.x;
    const int r = t >> 3, c4 = (t & 7) * 4;
    const float4 v = *reinterpret_cast<const float4*>(&W[(size_t)(k0 + r) * Ncols + n0 + c4]);
    Ts[r][c4] = v.x; Ts[r][c4 + 1] = v.y; Ts[r][c4 + 2] = v.z; Ts[r][c4 + 3] = v.w;
    __syncthreads();
    float w0 = Ts[c4][r], w1 = Ts[c4 + 1][r], w2 = Ts[c4 + 2][r], w3 = Ts[c4 + 3][r];
    ushort4 hi, lo;
    hi.x = f2bf(w0); lo.x = f2bf(w0 - bf2f(hi.x));
    hi.y = f2bf(w1); lo.y = f2bf(w1 - bf2f(hi.y));
    hi.z = f2bf(w2); lo.z = f2bf(w2 - bf2f(hi.z));
    hi.w = f2bf(w3); lo.w = f2bf(w3 - bf2f(hi.w));
    const size_t base = (size_t)(n0 + r) * KP + k0 + c4;
    *reinterpret_cast<ushort4*>(&Bt[base])            = hi;
    *reinterpret_cast<ushort4*>(&Bt[base + DIMM])     = hi;
    *reinterpret_cast<ushort4*>(&Bt[base + 2 * DIMM]) = lo;
}

// ---------------------------------------------------------------------------
// bf16 MFMA GEMM (m97 structure), unchanged from round 2 (verified).
// ---------------------------------------------------------------------------
template<int EPI>
__global__ __launch_bounds__(256)
void gemm_mfma(const unsigned short* __restrict__ A, const unsigned short* __restrict__ Bt,
               const float* __restrict__ bias, float* __restrict__ out, int Ncols)
{
    __shared__ unsigned short As[128 * 32];
    __shared__ unsigned short Bs[128 * 32];

    const int tid  = threadIdx.x;
    const int w    = tid >> 6, lane = tid & 63;
    const int m0   = blockIdx.x * 128, n0 = blockIdx.y * 128;
    const int wm   = w >> 1, wn = w & 1;
    const int lm   = lane & 15, kb = lane >> 4;

    const char* Ag = (const char*)(A  + (size_t)(m0 + w * 32 + (lane >> 2)) * KP) + (lane & 3) * 16;
    const char* Bg = (const char*)(Bt + (size_t)(n0 + w * 32 + (lane >> 2)) * KP) + (lane & 3) * 16;
    char* AsB = (char*)As + w * 2048;
    char* BsB = (char*)Bs + w * 2048;
    const size_t rowskip = (size_t)16 * KP * 2;

    f32x4 acc[4][4] = {};

    for (int k0 = 0; k0 < KP; k0 += 32) {
        const size_t kb2 = (size_t)k0 * 2;
        gload_lds16(Ag + kb2,           AsB);
        gload_lds16(Ag + kb2 + rowskip, AsB + 1024);
        gload_lds16(Bg + kb2,           BsB);
        gload_lds16(Bg + kb2 + rowskip, BsB + 1024);
        __syncthreads();

        bf16x8 a[4], b[4];
        #pragma unroll
        for (int mf = 0; mf < 4; ++mf)
            a[mf] = *reinterpret_cast<const bf16x8*>(&As[(wm * 64 + mf * 16 + lm) * 32 + kb * 8]);
        #pragma unroll
        for (int nf = 0; nf < 4; ++nf)
            b[nf] = *reinterpret_cast<const bf16x8*>(&Bs[(wn * 64 + nf * 16 + lm) * 32 + kb * 8]);
        #pragma unroll
        for (int mf = 0; mf < 4; ++mf)
            #pragma unroll
            for (int nf = 0; nf < 4; ++nf)
                acc[mf][nf] = MFMA16(a[mf], b[nf], acc[mf][nf]);
        __syncthreads();
    }

    #pragma unroll
    for (int nf = 0; nf < 4; ++nf) {
        const int col = n0 + wn * 64 + nf * 16 + lm;
        const float bb = bias[col];
        #pragma unroll
        for (int mf = 0; mf < 4; ++mf) {
            #pragma unroll
            for (int r = 0; r < 4; ++r) {
                const int row = m0 + wm * 64 + mf * 16 + kb * 4 + r;
                const float c = acc[mf][nf][r] + bb;
                if (EPI == 0) {
                    out[(size_t)row * Ncols + col] = c;
                } else {
                    const int part = col / DIMM;
                    const int rem  = col - part * DIMM;
                    const int hh   = rem / HD;
                    const int d    = rem - hh * HD;
                    out[(((size_t)(part * NHEAD + hh)) * N_TOK + row) * HD + d] = c;
                }
            }
        }
    }
}

// ---------------------------------------------------------------------------
// Rotary: q fp32 in place; K -> packed bf16 hi/lo planes [h][2][4096][104],
// scale 1/sqrt(80) folded into K, d=80..103 zeroed.
// ---------------------------------------------------------------------------
__global__ void rope_kernel(const float* __restrict__ freqs, float* __restrict__ q,
                            const float* __restrict__ k, unsigned short* __restrict__ Kp)
{
    const int idx = blockIdx.x * blockDim.x + threadIdx.x;
    if (idx >= N_TOK * NHEAD * 40) return;
    const int dp = idx % 40;
    const int t  = idx / 40;
    const int h  = t & 15;
    const int n  = t >> 4;

    const float f = freqs[n * 40 + dp];
    const float c = cosf(f);
    const float s = sinf(f);

    const size_t base = ((size_t)h * N_TOK + n) * HD;
    const float q1 = q[base + dp], q2 = q[base + dp + 40];
    q[base + dp]      = q1 * c - q2 * s;
    q[base + dp + 40] = q2 * c + q1 * s;

    const float scale = 0.11180339887498949f;
    const float k1 = k[base + dp], k2 = k[base + dp + 40];
    const float kr1 = (k1 * c - k2 * s) * scale;
    const float kr2 = (k2 * c + k1 * s) * scale;

    const size_t hi = ((size_t)(h * 2) * N_TOK + n) * 104;
    const size_t lo = ((size_t)(h * 2 + 1) * N_TOK + n) * 104;
    const unsigned short h1 = f2bf(kr1);
    Kp[hi + dp]      = h1;
    Kp[lo + dp]      = f2bf(kr1 - bf2f(h1));
    const unsigned short h2 = f2bf(kr2);
    Kp[hi + dp + 40] = h2;
    Kp[lo + dp + 40] = f2bf(kr2 - bf2f(h2));
    if (dp < 12) {
        Kp[hi + 80 + dp] = 0; Kp[hi + 92 + dp] = 0;
        Kp[lo + 80 + dp] = 0; Kp[lo + 92 + dp] = 0;
    }
}

// ---------------------------------------------------------------------------
// V^T pack: vbuf[h][n][80] fp32 -> Vt[h][tile][2][80][40] bf16 (hi,lo),
// keys padded 32->40 (pad zeroed; never enters MFMA, only bank spreading).
// ---------------------------------------------------------------------------
__global__ __launch_bounds__(256)
void vpack_kernel(const float* __restrict__ v, unsigned short* __restrict__ Vt)
{
    __shared__ float T[32][81];
    const int t = blockIdx.x, h = blockIdx.y;
    const int kt = t * 32;
    for (int e = threadIdx.x; e < 32 * 80; e += 256) {
        const int key = e / 80, d = e - (e / 80) * 80;
        T[key][d] = v[((size_t)h * N_TOK + kt + key) * HD + d];
    }
    __syncthreads();
    unsigned short* base = Vt + ((size_t)h * 128 + t) * 6400;
    for (int e = threadIdx.x; e < 3200; e += 256) {
        const int d = e / 40, key = e - (e / 40) * 40;
        const float x = (key < 32) ? T[key][d] : 0.f;
        const unsigned short hi = f2bf(x);
        base[e]        = hi;
        base[3200 + e] = f2bf(x - bf2f(hi));
    }
}

// ---------------------------------------------------------------------------
// MFMA flash attention. 512 thr = 8 waves x 16 q-rows (128 rows/block).
// K/V staged by async global_load_lds from pre-packed bf16, double-buffered,
// ONE barrier per 32-key tile. Segment mask per-lane. Epilogue writes packed
// A' rows [hi|lo|hi] for the proj GEMM.
// ---------------------------------------------------------------------------
__global__ __launch_bounds__(512, 2)
void attn_mfma(const float* __restrict__ qbuf, const unsigned short* __restrict__ Kp,
               const unsigned short* __restrict__ Vt, const int* __restrict__ cu,
               unsigned short* __restrict__ Ap)
{
    __shared__ __align__(16) unsigned short KhS[2][3328];   // [key32][104]
    __shared__ __align__(16) unsigned short KlS[2][3328];
    __shared__ __align__(16) unsigned short VS [2][6400];   // [2(hi,lo)][80][40]
    __shared__ __align__(16) unsigned short Pw [8][640];    // per-wave P [16][40]

    const int tid  = threadIdx.x;
    const int w    = tid >> 6, lane = tid & 63;
    const int lm   = lane & 15, g = lane >> 4;

    // XCD swizzle: each XCD (= lin&7, empirically) owns 2 heads -> L2 locality
    const int lin = blockIdx.x;
    const int h   = (lin & 7) * 2 + ((lin >> 3) & 1);
    const int q0  = (lin >> 4) * 128;

    const int c1 = cu[1], c2 = cu[2], c3 = cu[3];
    #define SEGOF(n) ((int)((n) >= c1) + (int)((n) >= c2) + (int)((n) >= c3))
    const int seg_first = SEGOF(q0);
    const int seg_last  = SEGOF(q0 + 127);
    const int cuv[5] = {0, c1, c2, c3, N_TOK};
    const int kmin = cuv[seg_first], kmax = cuv[seg_last + 1];
    const int kt0 = kmin & ~31;
    const int ntiles = (kmax - kt0 + 31) >> 5;

    const size_t hb = (size_t)h * N_TOK;

    // --- Q fragments hi/lo (scale already folded into K pack)
    bf16x8 qh[3], ql[3];
    {
        const int qrow = q0 + w * 16 + lm;
        const float* qp = qbuf + (hb + qrow) * HD;
        #pragma unroll
        for (int ks = 0; ks < 3; ++ks) {
            #pragma unroll
            for (int j = 0; j < 8; ++j) {
                const int d = ks * 32 + g * 8 + j;
                const float x = (d < HD) ? qp[d] : 0.f;
                const unsigned short hi = f2bf(x);
                qh[ks][j] = (short)hi;
                ql[ks][j] = (short)f2bf(x - bf2f(hi));
            }
        }
    }
    int qsg[4];
    #pragma unroll
    for (int r = 0; r < 4; ++r) qsg[r] = SEGOF(q0 + w * 16 + g * 4 + r);

    float mrun[4] = {-1e30f, -1e30f, -1e30f, -1e30f};
    float lrun[4] = {0.f, 0.f, 0.f, 0.f};
    f32x4 accO[5] = {};

    // --- async staging: 27 gload_lds (16B/lane) split across the 8 waves
    auto issue = [&](int buf, int kt) {
        const char* sK  = (const char*)(Kp + ((size_t)(h * 2)     * N_TOK + kt) * 104);
        const char* sKl = (const char*)(Kp + ((size_t)(h * 2 + 1) * N_TOK + kt) * 104);
        const char* sV  = (const char*)(Vt + ((size_t)h * 128 + (kt >> 5)) * 6400);
        char* dK  = (char*)&KhS[buf][0];
        char* dKl = (char*)&KlS[buf][0];
        char* dV  = (char*)&VS[buf][0];
        for (int j = w; j < 27; j += 8) {
            const char* s; char* d; int off; int half;
            if (j < 7)       { s = sK;  d = dK;  off = j * 1024;        half = (j == 6); }
            else if (j < 14) { s = sKl; d = dKl; off = (j - 7) * 1024;  half = (j == 13); }
            else             { s = sV;  d = dV;  off = (j - 14) * 1024; half = (j == 26); }
            if (!half || lane < 32)
                gload_lds16(s + off + (size_t)lane * 16, d + off);
        }
    };

    issue(0, kt0);
    __syncthreads();   // implicit vmcnt(0) drain: tile 0 resident

    for (int ti = 0; ti < ntiles; ++ti) {
        const int kt  = kt0 + ti * 32;
        const int buf = ti & 1;
        if (ti + 1 < ntiles) issue(buf ^ 1, kt + 32);

        const unsigned short* Kh = &KhS[buf][0];
        const unsigned short* Kl = &KlS[buf][0];
        const unsigned short* Vb = &VS[buf][0];

        // ---- S = Q @ K^T (two 16-key halves, 3-term hi/lo)
        f32x4 s0 = {0.f, 0.f, 0.f, 0.f}, s1 = {0.f, 0.f, 0.f, 0.f};
        #pragma unroll
        for (int ks = 0; ks < 3; ++ks) {
            const bf16x8 k0h = *reinterpret_cast<const bf16x8*>(&Kh[lm * 104 + ks * 32 + g * 8]);
            const bf16x8 k0l = *reinterpret_cast<const bf16x8*>(&Kl[lm * 104 + ks * 32 + g * 8]);
            const bf16x8 k1h = *reinterpret_cast<const bf16x8*>(&Kh[(16 + lm) * 104 + ks * 32 + g * 8]);
            const bf16x8 k1l = *reinterpret_cast<const bf16x8*>(&Kl[(16 + lm) * 104 + ks * 32 + g * 8]);
            s0 = MFMA16(qh[ks], k0h, s0);
            s0 = MFMA16(ql[ks], k0h, s0);
            s0 = MFMA16(qh[ks], k0l, s0);
            s1 = MFMA16(qh[ks], k1h, s1);
            s1 = MFMA16(ql[ks], k1h, s1);
            s1 = MFMA16(qh[ks], k1l, s1);
        }

        // ---- online softmax (per-lane segment mask; 16-lane butterfly)
        const int ks0 = SEGOF(kt + lm), ks1 = SEGOF(kt + 16 + lm);
        float sfr[4], p0v[4], p1v[4];
        #pragma unroll
        for (int r = 0; r < 4; ++r) {
            const bool u0 = (ks0 == qsg[r]), u1 = (ks1 == qsg[r]);
            float v0 = u0 ? s0[r] : -1e30f;
            float v1 = u1 ? s1[r] : -1e30f;
            float tm = fmaxf(v0, v1);
            tm = fmaxf(tm, __shfl_xor(tm, 1));
            tm = fmaxf(tm, __shfl_xor(tm, 2));
            tm = fmaxf(tm, __shfl_xor(tm, 4));
            tm = fmaxf(tm, __shfl_xor(tm, 8));
            const float mo = mrun[r];
            const float mn = fmaxf(mo, tm);
            const float sc = __expf(mo - mn);
            const float e0 = u0 ? __expf(s0[r] - mn) : 0.f;
            const float e1 = u1 ? __expf(s1[r] - mn) : 0.f;
            float rs = e0 + e1;
            rs += __shfl_xor(rs, 1);
            rs += __shfl_xor(rs, 2);
            rs += __shfl_xor(rs, 4);
            rs += __shfl_xor(rs, 8);
            lrun[r] = lrun[r] * sc + rs;
            mrun[r] = mn;
            sfr[r] = sc; p0v[r] = e0; p1v[r] = e1;
        }
        #pragma unroll
        for (int r = 0; r < 4; ++r) {
            Pw[w][(g * 4 + r) * 40 + lm]      = f2bf(p0v[r]);
            Pw[w][(g * 4 + r) * 40 + 16 + lm] = f2bf(p1v[r]);
        }
        asm volatile("s_waitcnt lgkmcnt(0)" ::: "memory");
        __builtin_amdgcn_sched_barrier(0);

        // ---- O = O*sf + P @ (Vh + Vl)
        const bf16x8 pa = *reinterpret_cast<const bf16x8*>(&Pw[w][lm * 40 + g * 8]);
        #pragma unroll
        for (int f = 0; f < 5; ++f) {
            const bf16x8 vh = *reinterpret_cast<const bf16x8*>(&Vb[(f * 16 + lm) * 40 + g * 8]);
            const bf16x8 vl = *reinterpret_cast<const bf16x8*>(&Vb[3200 + (f * 16 + lm) * 40 + g * 8]);
            f32x4 t = accO[f];
            t[0] *= sfr[0]; t[1] *= sfr[1]; t[2] *= sfr[2]; t[3] *= sfr[3];
            t = MFMA16(pa, vh, t);
            t = MFMA16(pa, vl, t);
            accO[f] = t;
        }

        __syncthreads();   // drains this wave's gloads for tile ti+1; protects buf reuse
    }

    // ---- epilogue: write packed A' rows [hi | lo | hi]
    #pragma unroll
    for (int r = 0; r < 4; ++r) {
        const float inv = 1.f / lrun[r];
        const int n = q0 + w * 16 + g * 4 + r;
        const size_t rb = (size_t)n * KP + h * HD;
        #pragma unroll
        for (int f = 0; f < 5; ++f) {
            const float v = accO[f][r] * inv;
            const unsigned short hi = f2bf(v);
            const unsigned short lo = f2bf(v - bf2f(hi));
            Ap[rb + f * 16 + lm]            = hi;
            Ap[rb + DIMM + f * 16 + lm]     = lo;
            Ap[rb + 2 * DIMM + f * 16 + lm] = hi;
        }
    }
    #undef SEGOF
}

// ---------------------------------------------------------------------------
extern "C" void kernel_launch(void* const* d_in, const int* in_sizes, int n_in,
                              void* d_out, int out_size, void* d_ws, size_t ws_size,
                              hipStream_t stream)
{
    const float* hidden = (const float*)d_in[0];
    const int*   cu     = (const int*)  d_in[1];
    const float* rope   = (const float*)d_in[2];
    const float* w_qkv  = (const float*)d_in[3];
    const float* b_qkv  = (const float*)d_in[4];
    const float* w_proj = (const float*)d_in[5];
    const float* b_proj = (const float*)d_in[6];
    float*       out    = (float*)d_out;

    const size_t perbuf = (size_t)NHEAD * N_TOK * HD;          // 5,242,880 floats
    float* qbuf = (float*)d_ws;
    float* kbuf = qbuf + perbuf;
    float* vbuf = kbuf + perbuf;
    unsigned short* Apack = (unsigned short*)(vbuf + perbuf);  // [4096][3840]
    unsigned short* BtQ   = Apack + (size_t)N_TOK * KP;        // [3840][3840]
    unsigned short* BtP   = BtQ + (size_t)QKVN * KP;           // [1280][3840]
    unsigned short* Vt    = BtP + (size_t)DIMM * KP;           // [16][128][2][80][40]
    unsigned short* Kp    = BtQ;   // overlay: BtQ dead after qkv GEMM

    pack_A_kernel<<<(N_TOK * DIMM / 4 + 255) / 256, 256, 0, stream>>>(hidden, Apack);
    pack_Bt_kernel<<<dim3(DIMM / 32, QKVN / 32), 256, 0, stream>>>(w_qkv, BtQ, QKVN);
    pack_Bt_kernel<<<dim3(DIMM / 32, DIMM / 32), 256, 0, stream>>>(w_proj, BtP, DIMM);

    gemm_mfma<1><<<dim3(N_TOK / 128, QKVN / 128), 256, 0, stream>>>(Apack, BtQ, b_qkv, qbuf, QKVN);

    rope_kernel<<<(N_TOK * NHEAD * 40 + 255) / 256, 256, 0, stream>>>(rope, qbuf, kbuf, Kp);
    vpack_kernel<<<dim3(128, NHEAD), 256, 0, stream>>>(vbuf, Vt);

    attn_mfma<<<512, 512, 0, stream>>>(qbuf, Kp, Vt, cu, Apack);

    gemm_mfma<0><<<dim3(N_TOK / 128, DIMM / 128), 256, 0, stream>>>(Apack, BtP, b_proj, out, DIMM);
}

// Round 5
// 564.587 us; speedup vs baseline: 4.3349x; 1.1053x over previous
//
#include <hip/hip_runtime.h>
#include <math.h>

// ============================================================================
// VisionAttention round 4 (resubmit — round-4 bench died on GPU acquisition).
//   Round-3 bottleneck: attn softmax serialization (32 shfl + 12 exp per
//   tile/wave, VALUBusy:MfmaUtil = 3:1). Fix: SWAPPED QK^T (S = mfma(K,Q)) so
//   each lane owns one q-row -> in-register row reduce + 2 shfls; defer-max
//   (THR=8) skips rescale on most tiles. GEMMs: bijective XCD swizzle.
// ============================================================================

#define N_TOK 4096
#define DIMM  1280
#define NHEAD 16
#define HD    80
#define QKVN  3840
#define KP    3840   // packed K' = 3*DIMM for the hi/lo GEMM trick

typedef short bf16x8 __attribute__((ext_vector_type(8)));
typedef float f32x4  __attribute__((ext_vector_type(4)));

__device__ __forceinline__ unsigned short f2bf(float x) {
    unsigned int u = __float_as_uint(x);
    u += 0x7fff + ((u >> 16) & 1);           // RNE
    return (unsigned short)(u >> 16);
}
__device__ __forceinline__ float bf2f(unsigned short h) {
    return __uint_as_float(((unsigned int)h) << 16);
}
__device__ __forceinline__ void gload_lds16(const void* g, void* l) {
    __builtin_amdgcn_global_load_lds(
        (const __attribute__((address_space(1))) unsigned int*)g,
        (__attribute__((address_space(3))) unsigned int*)l, 16, 0, 0);
}

#define MFMA16(a, b, c) __builtin_amdgcn_mfma_f32_16x16x32_bf16((a), (b), (c), 0, 0, 0)

// ---------------------------------------------------------------------------
// pack hidden: X[M][1280] fp32 -> Ap[M][3840] bf16 = [hi | lo | hi]
// ---------------------------------------------------------------------------
__global__ void pack_A_kernel(const float* __restrict__ X, unsigned short* __restrict__ Ap)
{
    const int idx = blockIdx.x * blockDim.x + threadIdx.x;
    if (idx >= N_TOK * DIMM / 4) return;
    const int e = idx * 4;
    const int m = e / DIMM, k = e - (e / DIMM) * DIMM;
    const float4 v = *reinterpret_cast<const float4*>(&X[(size_t)m * DIMM + k]);
    ushort4 hi, lo;
    hi.x = f2bf(v.x); lo.x = f2bf(v.x - bf2f(hi.x));
    hi.y = f2bf(v.y); lo.y = f2bf(v.y - bf2f(hi.y));
    hi.z = f2bf(v.z); lo.z = f2bf(v.z - bf2f(hi.z));
    hi.w = f2bf(v.w); lo.w = f2bf(v.w - bf2f(hi.w));
    const size_t base = (size_t)m * KP + k;
    *reinterpret_cast<ushort4*>(&Ap[base])            = hi;
    *reinterpret_cast<ushort4*>(&Ap[base + DIMM])     = lo;
    *reinterpret_cast<ushort4*>(&Ap[base + 2 * DIMM]) = hi;
}

// ---------------------------------------------------------------------------
// pack weight transposed: W[1280][Ncols] fp32 -> Bt[Ncols][3840] = [hi | hi | lo]
// ---------------------------------------------------------------------------
__global__ __launch_bounds__(256)
void pack_Bt_kernel(const float* __restrict__ W, unsigned short* __restrict__ Bt, int Ncols)
{
    __shared__ float Ts[32][33];
    const int k0 = blockIdx.x * 32, n0 = blockIdx.y * 32;
    const int t = threadIdx.x;
    const int r = t >> 3, c4 = (t & 7) * 4;
    const float4 v = *reinterpret_cast<const float4*>(&W[(size_t)(k0 + r) * Ncols + n0 + c4]);
    Ts[r][c4] = v.x; Ts[r][c4 + 1] = v.y; Ts[r][c4 + 2] = v.z; Ts[r][c4 + 3] = v.w;
    __syncthreads();
    float w0 = Ts[c4][r], w1 = Ts[c4 + 1][r], w2 = Ts[c4 + 2][r], w3 = Ts[c4 + 3][r];
    ushort4 hi, lo;
    hi.x = f2bf(w0); lo.x = f2bf(w0 - bf2f(hi.x));
    hi.y = f2bf(w1); lo.y = f2bf(w1 - bf2f(hi.y));
    hi.z = f2bf(w2); lo.z = f2bf(w2 - bf2f(hi.z));
    hi.w = f2bf(w3); lo.w = f2bf(w3 - bf2f(hi.w));
    const size_t base = (size_t)(n0 + r) * KP + k0 + c4;
    *reinterpret_cast<ushort4*>(&Bt[base])            = hi;
    *reinterpret_cast<ushort4*>(&Bt[base + DIMM])     = hi;
    *reinterpret_cast<ushort4*>(&Bt[base + 2 * DIMM]) = lo;
}

// ---------------------------------------------------------------------------
// bf16 MFMA GEMM (m97 structure) + bijective XCD swizzle (1D grid).
// ---------------------------------------------------------------------------
template<int EPI>
__global__ __launch_bounds__(256)
void gemm_mfma(const unsigned short* __restrict__ A, const unsigned short* __restrict__ Bt,
               const float* __restrict__ bias, float* __restrict__ out, int Ncols, int nwg)
{
    __shared__ unsigned short As[128 * 32];
    __shared__ unsigned short Bs[128 * 32];

    const int tid  = threadIdx.x;
    const int w    = tid >> 6, lane = tid & 63;

    // bijective XCD swizzle (nwg % 8 == 0): each XCD gets contiguous chunk
    const int lin = blockIdx.x;
    const int wg  = (lin & 7) * (nwg >> 3) + (lin >> 3);
    const int m0  = (wg & 31) * 128;          // 4096/128 = 32 M-blocks, fastest
    const int n0  = (wg >> 5) * 128;

    const int wm   = w >> 1, wn = w & 1;
    const int lm   = lane & 15, kb = lane >> 4;

    const char* Ag = (const char*)(A  + (size_t)(m0 + w * 32 + (lane >> 2)) * KP) + (lane & 3) * 16;
    const char* Bg = (const char*)(Bt + (size_t)(n0 + w * 32 + (lane >> 2)) * KP) + (lane & 3) * 16;
    char* AsB = (char*)As + w * 2048;
    char* BsB = (char*)Bs + w * 2048;
    const size_t rowskip = (size_t)16 * KP * 2;

    f32x4 acc[4][4] = {};

    for (int k0 = 0; k0 < KP; k0 += 32) {
        const size_t kb2 = (size_t)k0 * 2;
        gload_lds16(Ag + kb2,           AsB);
        gload_lds16(Ag + kb2 + rowskip, AsB + 1024);
        gload_lds16(Bg + kb2,           BsB);
        gload_lds16(Bg + kb2 + rowskip, BsB + 1024);
        __syncthreads();

        bf16x8 a[4], b[4];
        #pragma unroll
        for (int mf = 0; mf < 4; ++mf)
            a[mf] = *reinterpret_cast<const bf16x8*>(&As[(wm * 64 + mf * 16 + lm) * 32 + kb * 8]);
        #pragma unroll
        for (int nf = 0; nf < 4; ++nf)
            b[nf] = *reinterpret_cast<const bf16x8*>(&Bs[(wn * 64 + nf * 16 + lm) * 32 + kb * 8]);
        #pragma unroll
        for (int mf = 0; mf < 4; ++mf)
            #pragma unroll
            for (int nf = 0; nf < 4; ++nf)
                acc[mf][nf] = MFMA16(a[mf], b[nf], acc[mf][nf]);
        __syncthreads();
    }

    #pragma unroll
    for (int nf = 0; nf < 4; ++nf) {
        const int col = n0 + wn * 64 + nf * 16 + lm;
        const float bb = bias[col];
        #pragma unroll
        for (int mf = 0; mf < 4; ++mf) {
            #pragma unroll
            for (int r = 0; r < 4; ++r) {
                const int row = m0 + wm * 64 + mf * 16 + kb * 4 + r;
                const float c = acc[mf][nf][r] + bb;
                if (EPI == 0) {
                    out[(size_t)row * Ncols + col] = c;
                } else {
                    const int part = col / DIMM;
                    const int rem  = col - part * DIMM;
                    const int hh   = rem / HD;
                    const int d    = rem - hh * HD;
                    out[(((size_t)(part * NHEAD + hh)) * N_TOK + row) * HD + d] = c;
                }
            }
        }
    }
}

// ---------------------------------------------------------------------------
// Rotary: q fp32 in place; K -> packed bf16 hi/lo planes [h][2][4096][104],
// scale 1/sqrt(80) folded into K, d=80..103 zeroed.
// ---------------------------------------------------------------------------
__global__ void rope_kernel(const float* __restrict__ freqs, float* __restrict__ q,
                            const float* __restrict__ k, unsigned short* __restrict__ Kp)
{
    const int idx = blockIdx.x * blockDim.x + threadIdx.x;
    if (idx >= N_TOK * NHEAD * 40) return;
    const int dp = idx % 40;
    const int t  = idx / 40;
    const int h  = t & 15;
    const int n  = t >> 4;

    const float f = freqs[n * 40 + dp];
    const float c = cosf(f);
    const float s = sinf(f);

    const size_t base = ((size_t)h * N_TOK + n) * HD;
    const float q1 = q[base + dp], q2 = q[base + dp + 40];
    q[base + dp]      = q1 * c - q2 * s;
    q[base + dp + 40] = q2 * c + q1 * s;

    const float scale = 0.11180339887498949f;
    const float k1 = k[base + dp], k2 = k[base + dp + 40];
    const float kr1 = (k1 * c - k2 * s) * scale;
    const float kr2 = (k2 * c + k1 * s) * scale;

    const size_t hi = ((size_t)(h * 2) * N_TOK + n) * 104;
    const size_t lo = ((size_t)(h * 2 + 1) * N_TOK + n) * 104;
    const unsigned short h1 = f2bf(kr1);
    Kp[hi + dp]      = h1;
    Kp[lo + dp]      = f2bf(kr1 - bf2f(h1));
    const unsigned short h2 = f2bf(kr2);
    Kp[hi + dp + 40] = h2;
    Kp[lo + dp + 40] = f2bf(kr2 - bf2f(h2));
    if (dp < 12) {
        Kp[hi + 80 + dp] = 0; Kp[hi + 92 + dp] = 0;
        Kp[lo + 80 + dp] = 0; Kp[lo + 92 + dp] = 0;
    }
}

// ---------------------------------------------------------------------------
// V^T pack: vbuf[h][n][80] fp32 -> Vt[h][tile][2][80][40] bf16 (hi,lo)
// ---------------------------------------------------------------------------
__global__ __launch_bounds__(256)
void vpack_kernel(const float* __restrict__ v, unsigned short* __restrict__ Vt)
{
    __shared__ float T[32][81];
    const int t = blockIdx.x, h = blockIdx.y;
    const int kt = t * 32;
    for (int e = threadIdx.x; e < 32 * 80; e += 256) {
        const int key = e / 80, d = e - (e / 80) * 80;
        T[key][d] = v[((size_t)h * N_TOK + kt + key) * HD + d];
    }
    __syncthreads();
    unsigned short* base = Vt + ((size_t)h * 128 + t) * 6400;
    for (int e = threadIdx.x; e < 3200; e += 256) {
        const int d = e / 40, key = e - (e / 40) * 40;
        const float x = (key < 32) ? T[key][d] : 0.f;
        const unsigned short hi = f2bf(x);
        base[e]        = hi;
        base[3200 + e] = f2bf(x - bf2f(hi));
    }
}

// ---------------------------------------------------------------------------
// MFMA flash attention, SWAPPED QK^T: S = mfma(K,Q) puts one q-row per lane
// (q = lane&15), keys in regs across g-groups. Row softmax = in-reg reduce +
// 2 shfls; defer-max skips rescale. 512 thr = 8 waves x 16 q-rows.
// ---------------------------------------------------------------------------
__global__ __launch_bounds__(512)
void attn_mfma(const float* __restrict__ qbuf, const unsigned short* __restrict__ Kp,
               const unsigned short* __restrict__ Vt, const int* __restrict__ cu,
               unsigned short* __restrict__ Ap)
{
    __shared__ __align__(16) unsigned short KhS[2][3328];   // [key32][104]
    __shared__ __align__(16) unsigned short KlS[2][3328];
    __shared__ __align__(16) unsigned short VS [2][6400];   // [2(hi,lo)][80][40]
    __shared__ __align__(16) unsigned short Pw [8][640];    // per-wave P [q16][40]

    const int tid  = threadIdx.x;
    const int w    = tid >> 6, lane = tid & 63;
    const int lm   = lane & 15, g = lane >> 4;

    const int lin = blockIdx.x;
    const int h   = (lin & 7) * 2 + ((lin >> 3) & 1);
    const int q0  = (lin >> 4) * 128;

    const int c1 = cu[1], c2 = cu[2], c3 = cu[3];
    #define SEGOF(n) ((int)((n) >= c1) + (int)((n) >= c2) + (int)((n) >= c3))
    const int seg_first = SEGOF(q0);
    const int seg_last  = SEGOF(q0 + 127);
    const int cuv[5] = {0, c1, c2, c3, N_TOK};
    const int kmin = cuv[seg_first], kmax = cuv[seg_last + 1];
    const int kt0 = kmin & ~31;
    const int ntiles = (kmax - kt0 + 31) >> 5;

    const size_t hb = (size_t)h * N_TOK;

    // --- Q fragments hi/lo (B-operand: lane&15 = q-col, g = k-chunk)
    bf16x8 qh[3], ql[3];
    const int qrow = q0 + w * 16 + lm;
    {
        const float* qp = qbuf + (hb + qrow) * HD;
        #pragma unroll
        for (int ks = 0; ks < 3; ++ks) {
            #pragma unroll
            for (int j = 0; j < 8; ++j) {
                const int d = ks * 32 + g * 8 + j;
                const float x = (d < HD) ? qp[d] : 0.f;
                const unsigned short hi = f2bf(x);
                qh[ks][j] = (short)hi;
                ql[ks][j] = (short)f2bf(x - bf2f(hi));
            }
        }
    }
    // per-lane q-row segment bounds
    const int sq  = SEGOF(qrow);
    const int klo = cuv[sq], khi = cuv[sq + 1];

    float mrow = -1e30f, lrow = 0.f;
    f32x4 accO[5] = {};

    // --- async staging: 27 gload_lds (16B/lane) split across the 8 waves
    auto issue = [&](int buf, int kt) {
        const char* sK  = (const char*)(Kp + ((size_t)(h * 2)     * N_TOK + kt) * 104);
        const char* sKl = (const char*)(Kp + ((size_t)(h * 2 + 1) * N_TOK + kt) * 104);
        const char* sV  = (const char*)(Vt + ((size_t)h * 128 + (kt >> 5)) * 6400);
        char* dK  = (char*)&KhS[buf][0];
        char* dKl = (char*)&KlS[buf][0];
        char* dV  = (char*)&VS[buf][0];
        for (int j = w; j < 27; j += 8) {
            const char* s; char* d; int off; int half;
            if (j < 7)       { s = sK;  d = dK;  off = j * 1024;        half = (j == 6); }
            else if (j < 14) { s = sKl; d = dKl; off = (j - 7) * 1024;  half = (j == 13); }
            else             { s = sV;  d = dV;  off = (j - 14) * 1024; half = (j == 26); }
            if (!half || lane < 32)
                gload_lds16(s + off + (size_t)lane * 16, d + off);
        }
    };

    issue(0, kt0);
    __syncthreads();

    for (int ti = 0; ti < ntiles; ++ti) {
        const int kt  = kt0 + ti * 32;
        const int buf = ti & 1;
        if (ti + 1 < ntiles) issue(buf ^ 1, kt + 32);

        const unsigned short* Kh = &KhS[buf][0];
        const unsigned short* Kl = &KlS[buf][0];
        const unsigned short* Vb = &VS[buf][0];

        // ---- S^T = K @ Q^T : lane holds S[q=lm][keys g*4+r | 16+g*4+r]
        f32x4 s0 = {0.f, 0.f, 0.f, 0.f}, s1 = {0.f, 0.f, 0.f, 0.f};
        #pragma unroll
        for (int ks = 0; ks < 3; ++ks) {
            const bf16x8 k0h = *reinterpret_cast<const bf16x8*>(&Kh[lm * 104 + ks * 32 + g * 8]);
            const bf16x8 k0l = *reinterpret_cast<const bf16x8*>(&Kl[lm * 104 + ks * 32 + g * 8]);
            const bf16x8 k1h = *reinterpret_cast<const bf16x8*>(&Kh[(16 + lm) * 104 + ks * 32 + g * 8]);
            const bf16x8 k1l = *reinterpret_cast<const bf16x8*>(&Kl[(16 + lm) * 104 + ks * 32 + g * 8]);
            s0 = MFMA16(k0h, qh[ks], s0);
            s0 = MFMA16(k0h, ql[ks], s0);
            s0 = MFMA16(k0l, qh[ks], s0);
            s1 = MFMA16(k1h, qh[ks], s1);
            s1 = MFMA16(k1h, ql[ks], s1);
            s1 = MFMA16(k1l, qh[ks], s1);
        }

        // ---- per-reg key validity (q-row bounds, hoisted)
        bool v0m[4], v1m[4];
        #pragma unroll
        for (int r = 0; r < 4; ++r) {
            const int j0 = kt + g * 4 + r;
            const int j1 = j0 + 16;
            v0m[r] = (j0 >= klo) && (j0 < khi);
            v1m[r] = (j1 >= klo) && (j1 < khi);
        }

        // ---- row max: in-reg + 2 shfls
        float tm = -1e30f;
        #pragma unroll
        for (int r = 0; r < 4; ++r) {
            tm = fmaxf(tm, fmaxf(v0m[r] ? s0[r] : -1e30f, v1m[r] ? s1[r] : -1e30f));
        }
        tm = fmaxf(tm, __shfl_xor(tm, 16));
        tm = fmaxf(tm, __shfl_xor(tm, 32));

        // ---- defer-max: skip rescale when max growth <= 8
        const bool defer = __all(tm <= mrow + 8.0f);
        if (!defer) {
            const float mn = fmaxf(mrow, tm);
            const float sc = __expf(mrow - mn);
            mrow = mn;
            lrow *= sc;
            float scq[4];
            #pragma unroll
            for (int r = 0; r < 4; ++r) scq[r] = __shfl(sc, ((lane >> 4) << 2) + r);
            #pragma unroll
            for (int f = 0; f < 5; ++f) {
                accO[f][0] *= scq[0]; accO[f][1] *= scq[1];
                accO[f][2] *= scq[2]; accO[f][3] *= scq[3];
            }
        }

        // ---- P = exp(S - m), row sum
        float p0[4], p1[4], rs = 0.f;
        #pragma unroll
        for (int r = 0; r < 4; ++r) {
            p0[r] = v0m[r] ? __expf(s0[r] - mrow) : 0.f;
            p1[r] = v1m[r] ? __expf(s1[r] - mrow) : 0.f;
            rs += p0[r] + p1[r];
        }
        rs += __shfl_xor(rs, 16);
        rs += __shfl_xor(rs, 32);
        lrow += rs;

        // ---- P -> LDS [q][key] as packed b32 writes
        {
            unsigned int u;
            u = (unsigned int)f2bf(p0[0]) | ((unsigned int)f2bf(p0[1]) << 16);
            *reinterpret_cast<unsigned int*>(&Pw[w][lm * 40 + g * 4])      = u;
            u = (unsigned int)f2bf(p0[2]) | ((unsigned int)f2bf(p0[3]) << 16);
            *reinterpret_cast<unsigned int*>(&Pw[w][lm * 40 + g * 4 + 2])  = u;
            u = (unsigned int)f2bf(p1[0]) | ((unsigned int)f2bf(p1[1]) << 16);
            *reinterpret_cast<unsigned int*>(&Pw[w][lm * 40 + 16 + g * 4]) = u;
            u = (unsigned int)f2bf(p1[2]) | ((unsigned int)f2bf(p1[3]) << 16);
            *reinterpret_cast<unsigned int*>(&Pw[w][lm * 40 + 18 + g * 4]) = u;
        }
        asm volatile("s_waitcnt lgkmcnt(0)" ::: "memory");
        __builtin_amdgcn_sched_barrier(0);

        // ---- O += P @ (Vh + Vl)
        const bf16x8 pa = *reinterpret_cast<const bf16x8*>(&Pw[w][lm * 40 + g * 8]);
        #pragma unroll
        for (int f = 0; f < 5; ++f) {
            const bf16x8 vh = *reinterpret_cast<const bf16x8*>(&Vb[(f * 16 + lm) * 40 + g * 8]);
            const bf16x8 vl = *reinterpret_cast<const bf16x8*>(&Vb[3200 + (f * 16 + lm) * 40 + g * 8]);
            accO[f] = MFMA16(pa, vh, accO[f]);
            accO[f] = MFMA16(pa, vl, accO[f]);
        }

        __syncthreads();   // drains gloads for tile ti+1; protects buf reuse
    }

    // ---- epilogue: redistribute 1/l to O-fragment rows, write packed A'
    const float linv = 1.f / lrow;
    float invq[4];
    #pragma unroll
    for (int r = 0; r < 4; ++r) invq[r] = __shfl(linv, ((lane >> 4) << 2) + r);

    #pragma unroll
    for (int r = 0; r < 4; ++r) {
        const int n = q0 + w * 16 + g * 4 + r;
        const size_t rb = (size_t)n * KP + h * HD;
        #pragma unroll
        for (int f = 0; f < 5; ++f) {
            const float v = accO[f][r] * invq[r];
            const unsigned short hi = f2bf(v);
            const unsigned short lo = f2bf(v - bf2f(hi));
            Ap[rb + f * 16 + lm]            = hi;
            Ap[rb + DIMM + f * 16 + lm]     = lo;
            Ap[rb + 2 * DIMM + f * 16 + lm] = hi;
        }
    }
    #undef SEGOF
}

// ---------------------------------------------------------------------------
extern "C" void kernel_launch(void* const* d_in, const int* in_sizes, int n_in,
                              void* d_out, int out_size, void* d_ws, size_t ws_size,
                              hipStream_t stream)
{
    const float* hidden = (const float*)d_in[0];
    const int*   cu     = (const int*)  d_in[1];
    const float* rope   = (const float*)d_in[2];
    const float* w_qkv  = (const float*)d_in[3];
    const float* b_qkv  = (const float*)d_in[4];
    const float* w_proj = (const float*)d_in[5];
    const float* b_proj = (const float*)d_in[6];
    float*       out    = (float*)d_out;

    const size_t perbuf = (size_t)NHEAD * N_TOK * HD;          // 5,242,880 floats
    float* qbuf = (float*)d_ws;
    float* kbuf = qbuf + perbuf;
    float* vbuf = kbuf + perbuf;
    unsigned short* Apack = (unsigned short*)(vbuf + perbuf);  // [4096][3840]
    unsigned short* BtQ   = Apack + (size_t)N_TOK * KP;        // [3840][3840]
    unsigned short* BtP   = BtQ + (size_t)QKVN * KP;           // [1280][3840]
    unsigned short* Vt    = BtP + (size_t)DIMM * KP;           // [16][128][2][80][40]
    unsigned short* Kp    = BtQ;   // overlay: BtQ dead after qkv GEMM

    pack_A_kernel<<<(N_TOK * DIMM / 4 + 255) / 256, 256, 0, stream>>>(hidden, Apack);
    pack_Bt_kernel<<<dim3(DIMM / 32, QKVN / 32), 256, 0, stream>>>(w_qkv, BtQ, QKVN);
    pack_Bt_kernel<<<dim3(DIMM / 32, DIMM / 32), 256, 0, stream>>>(w_proj, BtP, DIMM);

    gemm_mfma<1><<<960, 256, 0, stream>>>(Apack, BtQ, b_qkv, qbuf, QKVN, 960);

    rope_kernel<<<(N_TOK * NHEAD * 40 + 255) / 256, 256, 0, stream>>>(rope, qbuf, kbuf, Kp);
    vpack_kernel<<<dim3(128, NHEAD), 256, 0, stream>>>(vbuf, Vt);

    attn_mfma<<<512, 512, 0, stream>>>(qbuf, Kp, Vt, cu, Apack);

    gemm_mfma<0><<<320, 256, 0, stream>>>(Apack, BtP, b_proj, out, DIMM, 320);
}

// Round 6
// 548.862 us; speedup vs baseline: 4.4591x; 1.0286x over previous
//
#include <hip/hip_runtime.h>
#include <math.h>

// ============================================================================
// VisionAttention round 6.
//   Round-5 finding: attn is ~90% stalled (MfmaUtil 3.3, VALU 7.9, Occ 5%) —
//   the per-tile __syncthreads drains vmcnt(0), serializing every tile on
//   full memory latency. Fix (T4): depth-2 prefetch + counted vmcnt(4/3) +
//   raw s_barriers; never drain mid-loop. P stays in registers via key-slot-
//   permuted V pack (MFMA k-order is free). GEMMs: 2D XCD tiles cut A refetch.
// ============================================================================

#define N_TOK 4096
#define DIMM  1280
#define NHEAD 16
#define HD    80
#define QKVN  3840
#define KP    3840   // packed K' = 3*DIMM for the hi/lo GEMM trick

typedef short bf16x8 __attribute__((ext_vector_type(8)));
typedef float f32x4  __attribute__((ext_vector_type(4)));

__device__ __forceinline__ unsigned short f2bf(float x) {
    unsigned int u = __float_as_uint(x);
    u += 0x7fff + ((u >> 16) & 1);           // RNE
    return (unsigned short)(u >> 16);
}
__device__ __forceinline__ float bf2f(unsigned short h) {
    return __uint_as_float(((unsigned int)h) << 16);
}
__device__ __forceinline__ void gload_lds16(const void* g, void* l) {
    __builtin_amdgcn_global_load_lds(
        (const __attribute__((address_space(1))) unsigned int*)g,
        (__attribute__((address_space(3))) unsigned int*)l, 16, 0, 0);
}

#define MFMA16(a, b, c) __builtin_amdgcn_mfma_f32_16x16x32_bf16((a), (b), (c), 0, 0, 0)

// ---------------------------------------------------------------------------
// pack hidden: X[M][1280] fp32 -> Ap[M][3840] bf16 = [hi | lo | hi]
// ---------------------------------------------------------------------------
__global__ void pack_A_kernel(const float* __restrict__ X, unsigned short* __restrict__ Ap)
{
    const int idx = blockIdx.x * blockDim.x + threadIdx.x;
    if (idx >= N_TOK * DIMM / 4) return;
    const int e = idx * 4;
    const int m = e / DIMM, k = e - (e / DIMM) * DIMM;
    const float4 v = *reinterpret_cast<const float4*>(&X[(size_t)m * DIMM + k]);
    ushort4 hi, lo;
    hi.x = f2bf(v.x); lo.x = f2bf(v.x - bf2f(hi.x));
    hi.y = f2bf(v.y); lo.y = f2bf(v.y - bf2f(hi.y));
    hi.z = f2bf(v.z); lo.z = f2bf(v.z - bf2f(hi.z));
    hi.w = f2bf(v.w); lo.w = f2bf(v.w - bf2f(hi.w));
    const size_t base = (size_t)m * KP + k;
    *reinterpret_cast<ushort4*>(&Ap[base])            = hi;
    *reinterpret_cast<ushort4*>(&Ap[base + DIMM])     = lo;
    *reinterpret_cast<ushort4*>(&Ap[base + 2 * DIMM]) = hi;
}

// ---------------------------------------------------------------------------
// pack weight transposed: W[1280][Ncols] fp32 -> Bt[Ncols][3840] = [hi | hi | lo]
// ---------------------------------------------------------------------------
__global__ __launch_bounds__(256)
void pack_Bt_kernel(const float* __restrict__ W, unsigned short* __restrict__ Bt, int Ncols)
{
    __shared__ float Ts[32][33];
    const int k0 = blockIdx.x * 32, n0 = blockIdx.y * 32;
    const int t = threadIdx.x;
    const int r = t >> 3, c4 = (t & 7) * 4;
    const float4 v = *reinterpret_cast<const float4*>(&W[(size_t)(k0 + r) * Ncols + n0 + c4]);
    Ts[r][c4] = v.x; Ts[r][c4 + 1] = v.y; Ts[r][c4 + 2] = v.z; Ts[r][c4 + 3] = v.w;
    __syncthreads();
    float w0 = Ts[c4][r], w1 = Ts[c4 + 1][r], w2 = Ts[c4 + 2][r], w3 = Ts[c4 + 3][r];
    ushort4 hi, lo;
    hi.x = f2bf(w0); lo.x = f2bf(w0 - bf2f(hi.x));
    hi.y = f2bf(w1); lo.y = f2bf(w1 - bf2f(hi.y));
    hi.z = f2bf(w2); lo.z = f2bf(w2 - bf2f(hi.z));
    hi.w = f2bf(w3); lo.w = f2bf(w3 - bf2f(hi.w));
    const size_t base = (size_t)(n0 + r) * KP + k0 + c4;
    *reinterpret_cast<ushort4*>(&Bt[base])            = hi;
    *reinterpret_cast<ushort4*>(&Bt[base + DIMM])     = hi;
    *reinterpret_cast<ushort4*>(&Bt[base + 2 * DIMM]) = lo;
}

// ---------------------------------------------------------------------------
// bf16 MFMA GEMM (m97 structure) + 2D XCD tiling for L2 locality.
// EPI==1 (qkv, 960 wg): XCD owns 8m x 15n blocks. EPI==0 (proj, 320): 4m x 10n.
// ---------------------------------------------------------------------------
template<int EPI>
__global__ __launch_bounds__(256)
void gemm_mfma(const unsigned short* __restrict__ A, const unsigned short* __restrict__ Bt,
               const float* __restrict__ bias, float* __restrict__ out, int Ncols)
{
    __shared__ unsigned short As[128 * 32];
    __shared__ unsigned short Bs[128 * 32];

    const int tid  = threadIdx.x;
    const int w    = tid >> 6, lane = tid & 63;

    // 2D XCD swizzle (blockIdx round-robins XCDs: xcd = lin & 7)
    const int lin = blockIdx.x;
    const int x   = lin & 7;
    const int l   = lin >> 3;
    int m0, n0;
    if (EPI == 1) {          // 960 wg = 32m x 30n; XCD x -> (mg = x>>1)*8m, (ng = x&1)*15n
        m0 = ((x >> 1) * 8 + (l & 7)) * 128;
        n0 = ((x & 1) * 15 + (l >> 3)) * 128;
    } else {                 // 320 wg = 32m x 10n; XCD x -> 4m x 10n
        m0 = (x * 4 + (l & 3)) * 128;
        n0 = (l >> 2) * 128;
    }

    const int wm   = w >> 1, wn = w & 1;
    const int lm   = lane & 15, kb = lane >> 4;

    const char* Ag = (const char*)(A  + (size_t)(m0 + w * 32 + (lane >> 2)) * KP) + (lane & 3) * 16;
    const char* Bg = (const char*)(Bt + (size_t)(n0 + w * 32 + (lane >> 2)) * KP) + (lane & 3) * 16;
    char* AsB = (char*)As + w * 2048;
    char* BsB = (char*)Bs + w * 2048;
    const size_t rowskip = (size_t)16 * KP * 2;

    f32x4 acc[4][4] = {};

    for (int k0 = 0; k0 < KP; k0 += 32) {
        const size_t kb2 = (size_t)k0 * 2;
        gload_lds16(Ag + kb2,           AsB);
        gload_lds16(Ag + kb2 + rowskip, AsB + 1024);
        gload_lds16(Bg + kb2,           BsB);
        gload_lds16(Bg + kb2 + rowskip, BsB + 1024);
        __syncthreads();

        bf16x8 a[4], b[4];
        #pragma unroll
        for (int mf = 0; mf < 4; ++mf)
            a[mf] = *reinterpret_cast<const bf16x8*>(&As[(wm * 64 + mf * 16 + lm) * 32 + kb * 8]);
        #pragma unroll
        for (int nf = 0; nf < 4; ++nf)
            b[nf] = *reinterpret_cast<const bf16x8*>(&Bs[(wn * 64 + nf * 16 + lm) * 32 + kb * 8]);
        #pragma unroll
        for (int mf = 0; mf < 4; ++mf)
            #pragma unroll
            for (int nf = 0; nf < 4; ++nf)
                acc[mf][nf] = MFMA16(a[mf], b[nf], acc[mf][nf]);
        __syncthreads();
    }

    #pragma unroll
    for (int nf = 0; nf < 4; ++nf) {
        const int col = n0 + wn * 64 + nf * 16 + lm;
        const float bb = bias[col];
        #pragma unroll
        for (int mf = 0; mf < 4; ++mf) {
            #pragma unroll
            for (int r = 0; r < 4; ++r) {
                const int row = m0 + wm * 64 + mf * 16 + kb * 4 + r;
                const float c = acc[mf][nf][r] + bb;
                if (EPI == 0) {
                    out[(size_t)row * Ncols + col] = c;
                } else {
                    const int part = col / DIMM;
                    const int rem  = col - part * DIMM;
                    const int hh   = rem / HD;
                    const int d    = rem - hh * HD;
                    out[(((size_t)(part * NHEAD + hh)) * N_TOK + row) * HD + d] = c;
                }
            }
        }
    }
}

// ---------------------------------------------------------------------------
// Rotary: q fp32 in place; K -> per-tile-contiguous bf16 hi/lo pack
// Kpk[h][tile128][plane2][32][104], scale folded, d-pad zeroed.
// ---------------------------------------------------------------------------
__global__ void rope_kernel(const float* __restrict__ freqs, float* __restrict__ q,
                            const float* __restrict__ k, unsigned short* __restrict__ Kpk)
{
    const int idx = blockIdx.x * blockDim.x + threadIdx.x;
    if (idx >= N_TOK * NHEAD * 40) return;
    const int dp = idx % 40;
    const int t  = idx / 40;
    const int h  = t & 15;
    const int n  = t >> 4;

    const float f = freqs[n * 40 + dp];
    const float c = cosf(f);
    const float s = sinf(f);

    const size_t base = ((size_t)h * N_TOK + n) * HD;
    const float q1 = q[base + dp], q2 = q[base + dp + 40];
    q[base + dp]      = q1 * c - q2 * s;
    q[base + dp + 40] = q2 * c + q1 * s;

    const float scale = 0.11180339887498949f;
    const float k1 = k[base + dp], k2 = k[base + dp + 40];
    const float kr1 = (k1 * c - k2 * s) * scale;
    const float kr2 = (k2 * c + k1 * s) * scale;

    const int tile = n >> 5, r = n & 31;
    const size_t hi = ((size_t)(h * 128 + tile) * 2 + 0) * 3328 + r * 104;
    const size_t lo = ((size_t)(h * 128 + tile) * 2 + 1) * 3328 + r * 104;
    const unsigned short h1 = f2bf(kr1);
    Kpk[hi + dp]      = h1;
    Kpk[lo + dp]      = f2bf(kr1 - bf2f(h1));
    const unsigned short h2 = f2bf(kr2);
    Kpk[hi + dp + 40] = h2;
    Kpk[lo + dp + 40] = f2bf(kr2 - bf2f(h2));
    if (dp < 12) {
        Kpk[hi + 80 + dp] = 0; Kpk[hi + 92 + dp] = 0;
        Kpk[lo + 80 + dp] = 0; Kpk[lo + 92 + dp] = 0;
    }
}

// ---------------------------------------------------------------------------
// V^T pack with KEY-SLOT PERMUTATION: Vt[h][tile][2][80][40] bf16, where
// column slot s holds key kappa(s) = ((s&7)<4 ? 0:16) + 4*(s>>3) + (s&3).
// This makes the PV A-fragment a pure local repack of the softmax registers.
// ---------------------------------------------------------------------------
__global__ __launch_bounds__(256)
void vpack_kernel(const float* __restrict__ v, unsigned short* __restrict__ Vt)
{
    __shared__ float T[32][81];
    const int t = blockIdx.x, h = blockIdx.y;
    const int kt = t * 32;
    for (int e = threadIdx.x; e < 32 * 80; e += 256) {
        const int key = e / 80, d = e - (e / 80) * 80;
        T[key][d] = v[((size_t)h * N_TOK + kt + key) * HD + d];
    }
    __syncthreads();
    unsigned short* base = Vt + ((size_t)h * 128 + t) * 6400;
    for (int e = threadIdx.x; e < 3200; e += 256) {
        const int d = e / 40, col = e - (e / 40) * 40;
        float x = 0.f;
        if (col < 32) {
            const int key = (((col & 7) < 4) ? 0 : 16) + 4 * (col >> 3) + (col & 3);
            x = T[key][d];
        }
        const unsigned short hi = f2bf(x);
        base[e]        = hi;
        base[3200 + e] = f2bf(x - bf2f(hi));
    }
}

// ---------------------------------------------------------------------------
// MFMA flash attention: swapped QK^T, in-register P, depth-2 counted-vmcnt
// pipeline (no vmcnt(0) drain mid-loop), raw s_barriers. 8 waves x 16 q-rows.
// LDS: KS[2][2][32][104] + VS[2][2][80][40] = 52224 B.
// ---------------------------------------------------------------------------
__global__ __launch_bounds__(512, 4)
void attn_mfma(const float* __restrict__ qbuf, const unsigned short* __restrict__ Kpk,
               const unsigned short* __restrict__ Vt, const int* __restrict__ cu,
               unsigned short* __restrict__ Ap)
{
    __shared__ __align__(16) unsigned short KS[2][6656];   // [buf][plane2*32*104]
    __shared__ __align__(16) unsigned short VS[2][6400];   // [buf][plane2*80*40]

    const int tid  = threadIdx.x;
    const int w    = tid >> 6, lane = tid & 63;
    const int lm   = lane & 15, g = lane >> 4;

    const int lin = blockIdx.x;
    const int h   = (lin & 7) * 2 + ((lin >> 3) & 1);
    const int q0  = (lin >> 4) * 128;

    const int c1 = cu[1], c2 = cu[2], c3 = cu[3];
    #define SEGOF(n) ((int)((n) >= c1) + (int)((n) >= c2) + (int)((n) >= c3))
    const int seg_first = SEGOF(q0);
    const int seg_last  = SEGOF(q0 + 127);
    const int cuv[5] = {0, c1, c2, c3, N_TOK};
    const int kmin = cuv[seg_first], kmax = cuv[seg_last + 1];
    const int kt0 = kmin & ~31;
    const int t0  = kt0 >> 5;
    const int ntiles = (kmax - kt0 + 31) >> 5;

    const size_t hb = (size_t)h * N_TOK;

    // --- Q fragments hi/lo (B-operand: lane&15 = q-col, g = k-chunk)
    bf16x8 qh[3], ql[3];
    const int qrow = q0 + w * 16 + lm;
    {
        const float* qp = qbuf + (hb + qrow) * HD;
        #pragma unroll
        for (int ks = 0; ks < 3; ++ks) {
            #pragma unroll
            for (int j = 0; j < 8; ++j) {
                const int d = ks * 32 + g * 8 + j;
                const float x = (d < HD) ? qp[d] : 0.f;
                const unsigned short hi = f2bf(x);
                qh[ks][j] = (short)hi;
                ql[ks][j] = (short)f2bf(x - bf2f(hi));
            }
        }
    }
    // per-lane q-row segment bounds
    const int sq  = SEGOF(qrow);
    const int klo = cuv[sq], khi = cuv[sq + 1];

    float mrow = -1e30f, lrow = 0.f;
    f32x4 accO[5] = {};

    // --- async staging: 26 x 1KB DMA chunks (last is 512B), waves 0-1: 4, 2-7: 3
    auto issue = [&](int buf, int tg) {
        const char* sK = (const char*)(Kpk + ((size_t)(h * 128 + tg) * 2) * 3328);
        const char* sV = (const char*)(Vt  +  (size_t)(h * 128 + tg) * 6400);
        char* dK = (char*)&KS[buf][0];
        char* dV = (char*)&VS[buf][0];
        for (int j = w; j < 26; j += 8) {
            if (j < 13) {
                gload_lds16(sK + j * 1024 + (size_t)lane * 16, dK + j * 1024);
            } else if (j < 25) {
                gload_lds16(sV + (j - 13) * 1024 + (size_t)lane * 16, dV + (j - 13) * 1024);
            } else if (lane < 32) {
                gload_lds16(sV + 12288 + (size_t)lane * 16, dV + 12288);
            }
        }
    };

    issue(0, t0);
    if (ntiles > 1) issue(1, t0 + 1);

    for (int ti = 0; ti < ntiles; ++ti) {
        const int buf = ti & 1;
        const int kt  = kt0 + ti * 32;

        // counted wait: my tile-ti loads landed; tile-ti+1's stay in flight
        if (ti + 1 < ntiles) {
            if (w < 2) asm volatile("s_waitcnt vmcnt(4)" ::: "memory");
            else       asm volatile("s_waitcnt vmcnt(3)" ::: "memory");
        } else {
            asm volatile("s_waitcnt vmcnt(0)" ::: "memory");
        }
        __builtin_amdgcn_s_barrier();      // all waves' ti loads landed
        asm volatile("" ::: "memory");

        const unsigned short* Kb = &KS[buf][0];
        const unsigned short* Vb = &VS[buf][0];

        // ---- S^T = K @ Q^T : lane holds S[q=lm][keys 4g+r | 16+4g+r]
        f32x4 s0 = {0.f, 0.f, 0.f, 0.f}, s1 = {0.f, 0.f, 0.f, 0.f};
        #pragma unroll
        for (int ks = 0; ks < 3; ++ks) {
            const bf16x8 k0h = *reinterpret_cast<const bf16x8*>(&Kb[lm * 104 + ks * 32 + g * 8]);
            const bf16x8 k0l = *reinterpret_cast<const bf16x8*>(&Kb[3328 + lm * 104 + ks * 32 + g * 8]);
            const bf16x8 k1h = *reinterpret_cast<const bf16x8*>(&Kb[(16 + lm) * 104 + ks * 32 + g * 8]);
            const bf16x8 k1l = *reinterpret_cast<const bf16x8*>(&Kb[3328 + (16 + lm) * 104 + ks * 32 + g * 8]);
            s0 = MFMA16(k0h, qh[ks], s0);
            s0 = MFMA16(k0h, ql[ks], s0);
            s0 = MFMA16(k0l, qh[ks], s0);
            s1 = MFMA16(k1h, qh[ks], s1);
            s1 = MFMA16(k1h, ql[ks], s1);
            s1 = MFMA16(k1l, qh[ks], s1);
        }

        // ---- per-reg key validity (q-row segment bounds, hoisted)
        bool v0m[4], v1m[4];
        #pragma unroll
        for (int r = 0; r < 4; ++r) {
            const int j0 = kt + g * 4 + r;
            const int j1 = j0 + 16;
            v0m[r] = (j0 >= klo) && (j0 < khi);
            v1m[r] = (j1 >= klo) && (j1 < khi);
        }

        // ---- row max: in-reg + 2 shfls
        float tm = -1e30f;
        #pragma unroll
        for (int r = 0; r < 4; ++r)
            tm = fmaxf(tm, fmaxf(v0m[r] ? s0[r] : -1e30f, v1m[r] ? s1[r] : -1e30f));
        tm = fmaxf(tm, __shfl_xor(tm, 16));
        tm = fmaxf(tm, __shfl_xor(tm, 32));

        // ---- defer-max: skip rescale when max growth <= 8
        const bool defer = __all(tm <= mrow + 8.0f);
        if (!defer) {
            const float mn = fmaxf(mrow, tm);
            const float sc = __expf(mrow - mn);
            mrow = mn;
            lrow *= sc;
            float scq[4];
            #pragma unroll
            for (int r = 0; r < 4; ++r) scq[r] = __shfl(sc, ((lane >> 4) << 2) + r);
            #pragma unroll
            for (int f = 0; f < 5; ++f) {
                accO[f][0] *= scq[0]; accO[f][1] *= scq[1];
                accO[f][2] *= scq[2]; accO[f][3] *= scq[3];
            }
        }

        // ---- P = exp(S - m), row sum
        float p0[4], p1[4], rs = 0.f;
        #pragma unroll
        for (int r = 0; r < 4; ++r) {
            p0[r] = v0m[r] ? __expf(s0[r] - mrow) : 0.f;
            p1[r] = v1m[r] ? __expf(s1[r] - mrow) : 0.f;
            rs += p0[r] + p1[r];
        }
        rs += __shfl_xor(rs, 16);
        rs += __shfl_xor(rs, 32);
        lrow += rs;

        // ---- A-fragment is a pure local repack (V pack is slot-permuted)
        bf16x8 pa;
        pa[0] = (short)f2bf(p0[0]); pa[1] = (short)f2bf(p0[1]);
        pa[2] = (short)f2bf(p0[2]); pa[3] = (short)f2bf(p0[3]);
        pa[4] = (short)f2bf(p1[0]); pa[5] = (short)f2bf(p1[1]);
        pa[6] = (short)f2bf(p1[2]); pa[7] = (short)f2bf(p1[3]);

        // ---- O += P @ (Vh + Vl)
        #pragma unroll
        for (int f = 0; f < 5; ++f) {
            const bf16x8 vh = *reinterpret_cast<const bf16x8*>(&Vb[(f * 16 + lm) * 40 + g * 8]);
            const bf16x8 vl = *reinterpret_cast<const bf16x8*>(&Vb[3200 + (f * 16 + lm) * 40 + g * 8]);
            accO[f] = MFMA16(pa, vh, accO[f]);
            accO[f] = MFMA16(pa, vl, accO[f]);
        }

        // all my LDS reads delivered -> buf free; then refill it for ti+2
        asm volatile("s_waitcnt lgkmcnt(0)" ::: "memory");
        __builtin_amdgcn_s_barrier();
        asm volatile("" ::: "memory");
        if (ti + 2 < ntiles) issue(buf, t0 + ti + 2);
    }

    // ---- epilogue: redistribute 1/l to O-fragment rows, write packed A'
    const float linv = 1.f / lrow;
    float invq[4];
    #pragma unroll
    for (int r = 0; r < 4; ++r) invq[r] = __shfl(linv, ((lane >> 4) << 2) + r);

    #pragma unroll
    for (int r = 0; r < 4; ++r) {
        const int n = q0 + w * 16 + g * 4 + r;
        const size_t rb = (size_t)n * KP + h * HD;
        #pragma unroll
        for (int f = 0; f < 5; ++f) {
            const float v = accO[f][r] * invq[r];
            const unsigned short hi = f2bf(v);
            const unsigned short lo = f2bf(v - bf2f(hi));
            Ap[rb + f * 16 + lm]            = hi;
            Ap[rb + DIMM + f * 16 + lm]     = lo;
            Ap[rb + 2 * DIMM + f * 16 + lm] = hi;
        }
    }
    #undef SEGOF
}

// ---------------------------------------------------------------------------
extern "C" void kernel_launch(void* const* d_in, const int* in_sizes, int n_in,
                              void* d_out, int out_size, void* d_ws, size_t ws_size,
                              hipStream_t stream)
{
    const float* hidden = (const float*)d_in[0];
    const int*   cu     = (const int*)  d_in[1];
    const float* rope   = (const float*)d_in[2];
    const float* w_qkv  = (const float*)d_in[3];
    const float* b_qkv  = (const float*)d_in[4];
    const float* w_proj = (const float*)d_in[5];
    const float* b_proj = (const float*)d_in[6];
    float*       out    = (float*)d_out;

    const size_t perbuf = (size_t)NHEAD * N_TOK * HD;          // 5,242,880 floats
    float* qbuf = (float*)d_ws;
    float* kbuf = qbuf + perbuf;
    float* vbuf = kbuf + perbuf;
    unsigned short* Apack = (unsigned short*)(vbuf + perbuf);  // [4096][3840]
    unsigned short* BtQ   = Apack + (size_t)N_TOK * KP;        // [3840][3840]
    unsigned short* BtP   = BtQ + (size_t)QKVN * KP;           // [1280][3840]
    unsigned short* Vt    = BtP + (size_t)DIMM * KP;           // [16][128][2][80][40]
    unsigned short* Kpk   = BtQ;   // overlay: BtQ dead after qkv GEMM (27.3MB<=29.5MB)

    pack_A_kernel<<<(N_TOK * DIMM / 4 + 255) / 256, 256, 0, stream>>>(hidden, Apack);
    pack_Bt_kernel<<<dim3(DIMM / 32, QKVN / 32), 256, 0, stream>>>(w_qkv, BtQ, QKVN);
    pack_Bt_kernel<<<dim3(DIMM / 32, DIMM / 32), 256, 0, stream>>>(w_proj, BtP, DIMM);

    gemm_mfma<1><<<960, 256, 0, stream>>>(Apack, BtQ, b_qkv, qbuf, QKVN);

    rope_kernel<<<(N_TOK * NHEAD * 40 + 255) / 256, 256, 0, stream>>>(rope, qbuf, kbuf, Kpk);
    vpack_kernel<<<dim3(128, NHEAD), 256, 0, stream>>>(vbuf, Vt);

    attn_mfma<<<512, 512, 0, stream>>>(qbuf, Kpk, Vt, cu, Apack);

    gemm_mfma<0><<<320, 256, 0, stream>>>(Apack, BtP, b_proj, out, DIMM);
}